// Round 2
// baseline (1322.631 us; speedup 1.0000x reference)
//
#include <hip/hip_runtime.h>
#include <stdint.h>

// OctFormer block, MI355X gfx950.
// Pipeline: [f2b data] [transpose weights] -> CPE+LN1 -> QKV GEMM -> attn ->
//           proj GEMM(+resid) -> LN2 -> FC1 GEMM(+gelu) -> FC2 GEMM(+resid -> d_out)
// Residual stream x lives in d_out (f32). GEMMs: bf16 MFMA 16x16x32, 128x128 tile,
// m97 structure (global_load_lds 16B staging, single LDS buffer, 2 barriers/K-step).

static constexpr int NPT   = 131072;  // points
static constexpr int CC    = 256;     // channels
static constexpr int NWIN  = 4096;    // windows
static constexpr int NHEAD = 8;

using u16 = unsigned short;
using u32 = unsigned int;

typedef __bf16 bf16x8 __attribute__((ext_vector_type(8)));
typedef float  f32x4  __attribute__((ext_vector_type(4)));
typedef u32    u32x4  __attribute__((ext_vector_type(4)));

__device__ __forceinline__ float b2f(u16 u) {
  union { float f; u32 i; } v; v.i = ((u32)u) << 16; return v.f;
}
__device__ __forceinline__ u16 f2b(float f) {  // RNE f32 -> bf16
  u32 x = __float_as_uint(f);
  return (u16)((x + 0x7fffu + ((x >> 16) & 1u)) >> 16);
}

__device__ __forceinline__ void gload_lds16(const void* g, void* l) {
  using gptr_t = const __attribute__((address_space(1))) uint32_t*;
  using lptr_t = __attribute__((address_space(3))) uint32_t*;
  __builtin_amdgcn_global_load_lds((gptr_t)(uintptr_t)g,
                                   (lptr_t)(uint32_t)(uintptr_t)l, 16, 0, 0);
}

// ---------------- f32 -> bf16 bulk convert ----------------
__global__ __launch_bounds__(256) void k_f2b(const float* __restrict__ in,
                                             u16* __restrict__ out, int n4) {
  for (int i = blockIdx.x * 256 + threadIdx.x; i < n4; i += gridDim.x * 256) {
    float4 v = ((const float4*)in)[i];
    ushort4 o;
    o.x = f2b(v.x); o.y = f2b(v.y); o.z = f2b(v.z); o.w = f2b(v.w);
    ((ushort4*)out)[i] = o;
  }
}

// ---------------- transpose + convert: out[c*R + r] = in[r*Cc + c] ----------------
__global__ __launch_bounds__(256) void k_transpose_f2b(const float* __restrict__ in,
                                                       u16* __restrict__ out, int R, int Cc) {
  int i = blockIdx.x * 256 + threadIdx.x;
  if (i >= R * Cc) return;
  int c = i / R, r = i - c * R;          // i = c*R + r : coalesced writes
  out[i] = f2b(in[r * Cc + c]);
}

// ---------------- CPE gather + residual + LN1 ----------------
__global__ __launch_bounds__(256) void k_cpe_ln1(
    const float* __restrict__ data, const int* __restrict__ nbr,
    const u16* __restrict__ datab, const float* __restrict__ w_cpe,
    const float* __restrict__ bn_g, const float* __restrict__ bn_b,
    const float* __restrict__ n1_g, const float* __restrict__ n1_b,
    float* __restrict__ xo, u16* __restrict__ ho) {
  const int n = blockIdx.x;
  const int c = threadIdx.x;
  const int* nb = nbr + n * 27;
  float acc = 0.f;
#pragma unroll
  for (int j = 0; j < 27; j++) {
    const int idx = nb[j];
    acc += b2f(datab[(size_t)idx * CC + c]) * w_cpe[j * CC + c];
  }
  const float xv = data[(size_t)n * CC + c] + acc * bn_g[c] + bn_b[c];
  xo[(size_t)n * CC + c] = xv;
  float s = xv, s2 = xv * xv;
#pragma unroll
  for (int m = 1; m <= 32; m <<= 1) { s += __shfl_xor(s, m); s2 += __shfl_xor(s2, m); }
  __shared__ float ps[4], ps2[4];
  const int wv = threadIdx.x >> 6;
  if ((threadIdx.x & 63) == 0) { ps[wv] = s; ps2[wv] = s2; }
  __syncthreads();
  s  = ps[0] + ps[1] + ps[2] + ps[3];
  s2 = ps2[0] + ps2[1] + ps2[2] + ps2[3];
  const float mean = s * (1.f / 256.f);
  const float var  = s2 * (1.f / 256.f) - mean * mean;
  const float inv  = rsqrtf(var + 1e-5f);
  ho[(size_t)n * CC + c] = f2b((xv - mean) * inv * n1_g[c] + n1_b[c]);
}

// ---------------- LN2 (wave per row) ----------------
__global__ __launch_bounds__(256) void k_ln2(const float* __restrict__ x,
                                             const float* __restrict__ g,
                                             const float* __restrict__ b,
                                             u16* __restrict__ h) {
  const int row = blockIdx.x * 4 + (threadIdx.x >> 6);
  const int l = threadIdx.x & 63;
  const float4 xv = ((const float4*)(x + (size_t)row * CC))[l];
  float s  = xv.x + xv.y + xv.z + xv.w;
  float s2 = xv.x * xv.x + xv.y * xv.y + xv.z * xv.z + xv.w * xv.w;
#pragma unroll
  for (int m = 1; m <= 32; m <<= 1) { s += __shfl_xor(s, m); s2 += __shfl_xor(s2, m); }
  const float mean = s * (1.f / 256.f);
  const float var  = s2 * (1.f / 256.f) - mean * mean;
  const float inv  = rsqrtf(var + 1e-5f);
  const int c = l * 4;
  ushort4 o;
  o.x = f2b((xv.x - mean) * inv * g[c + 0] + b[c + 0]);
  o.y = f2b((xv.y - mean) * inv * g[c + 1] + b[c + 1]);
  o.z = f2b((xv.z - mean) * inv * g[c + 2] + b[c + 2]);
  o.w = f2b((xv.w - mean) * inv * g[c + 3] + b[c + 3]);
  ((ushort4*)(h + (size_t)row * CC))[l] = o;
}

// ---------------- MFMA GEMM: C[M][ND] = A[M][KD] * Bt[ND][KD]^T ----------------
// EPI 0: out_bf16 = acc + bias
// EPI 1: out_f32 += acc + bias            (residual accumulate)
// EPI 2: out_bf16 = gelu_exact(acc + bias)
template <int KD, int ND, int EPI>
__global__ __launch_bounds__(256) void k_gemm(const u16* __restrict__ A,
                                              const u16* __restrict__ Bt,
                                              const float* __restrict__ bias,
                                              u16* __restrict__ outb,
                                              float* __restrict__ outf) {
  __shared__ __align__(16) u16 As[128 * 64];
  __shared__ __align__(16) u16 Bs[128 * 64];
  const int tid = threadIdx.x;
  const int lane = tid & 63;
  const int wv = tid >> 6;
  const int wm = (wv >> 1) * 64;
  const int wn = (wv & 1) * 64;
  const int l15 = lane & 15;
  const int lhi = lane >> 4;
  const int m0 = blockIdx.y * 128;
  const int n0 = blockIdx.x * 128;

  f32x4 acc[4][4] = {};

  for (int k0 = 0; k0 < KD; k0 += 64) {
#pragma unroll
    for (int i = 0; i < 4; i++) {
      const int off = i * 4096 + tid * 16;     // byte offset in 16KB tile
      const int row = off >> 7;                // 128B (=64 bf16) per row
      const int ke  = (off & 127) >> 1;        // element offset in K
      gload_lds16(A  + (size_t)(m0 + row) * KD + k0 + ke, (char*)As + off);
      gload_lds16(Bt + (size_t)(n0 + row) * KD + k0 + ke, (char*)Bs + off);
    }
    __syncthreads();
#pragma unroll
    for (int kk = 0; kk < 2; kk++) {
      bf16x8 fa[4], fb[4];
#pragma unroll
      for (int t = 0; t < 4; t++) {
        fa[t] = *(const bf16x8*)&As[(wm + t * 16 + l15) * 64 + kk * 32 + lhi * 8];
        fb[t] = *(const bf16x8*)&Bs[(wn + t * 16 + l15) * 64 + kk * 32 + lhi * 8];
      }
#pragma unroll
      for (int mi = 0; mi < 4; mi++)
#pragma unroll
        for (int ni = 0; ni < 4; ni++)
          acc[mi][ni] = __builtin_amdgcn_mfma_f32_16x16x32_bf16(fa[mi], fb[ni],
                                                                acc[mi][ni], 0, 0, 0);
    }
    __syncthreads();
  }

#pragma unroll
  for (int mi = 0; mi < 4; mi++) {
#pragma unroll
    for (int ni = 0; ni < 4; ni++) {
      const int col = n0 + wn + ni * 16 + l15;
      const float bc = bias[col];
#pragma unroll
      for (int r = 0; r < 4; r++) {
        const int row = m0 + wm + mi * 16 + lhi * 4 + r;
        const size_t o = (size_t)row * ND + col;
        float v = acc[mi][ni][r] + bc;
        if constexpr (EPI == 0) {
          outb[o] = f2b(v);
        } else if constexpr (EPI == 1) {
          outf[o] += v;
        } else {
          v = 0.5f * v * (1.0f + erff(v * 0.70710678118654752f));
          outb[o] = f2b(v);
        }
      }
    }
  }
}

// ---------------- windowed attention with RPE ----------------
// grid = NWIN*2 blocks, 256 threads; wave wv handles head (blockIdx.x&1)*4+wv.
__global__ __launch_bounds__(256) void k_attn(const u16* __restrict__ qkv,
                                              const int* __restrict__ rel_pos,
                                              const float* __restrict__ pmask,
                                              const float* __restrict__ rpet,
                                              u16* __restrict__ out) {
  __shared__ float sK[4][32][36];
  __shared__ float sV[4][32][36];
  const int nw  = blockIdx.x >> 1;
  const int grp = blockIdx.x & 1;
  const int wv  = threadIdx.x >> 6;
  const int hh  = grp * 4 + wv;
  const int lane = threadIdx.x & 63;
  const int p   = lane >> 1;    // row this lane stages / q-row it computes
  const int hlf = lane & 1;
  const int ds  = hlf * 16;

  const size_t rowbase = (size_t)(nw * 32 + p) * 768;

  // ---- stage K, V (f32) : this lane covers dims [ds, ds+16) of row p ----
  {
    const u16* kb = qkv + rowbase + 256 + hh * 32 + ds;
    u32x4 a0 = *(const u32x4*)kb;
    u32x4 a1 = *(const u32x4*)(kb + 8);
    float4* dk = (float4*)&sK[wv][p][ds];
    dk[0] = make_float4(b2f((u16)(a0[0] & 0xffff)), b2f((u16)(a0[0] >> 16)),
                        b2f((u16)(a0[1] & 0xffff)), b2f((u16)(a0[1] >> 16)));
    dk[1] = make_float4(b2f((u16)(a0[2] & 0xffff)), b2f((u16)(a0[2] >> 16)),
                        b2f((u16)(a0[3] & 0xffff)), b2f((u16)(a0[3] >> 16)));
    dk[2] = make_float4(b2f((u16)(a1[0] & 0xffff)), b2f((u16)(a1[0] >> 16)),
                        b2f((u16)(a1[1] & 0xffff)), b2f((u16)(a1[1] >> 16)));
    dk[3] = make_float4(b2f((u16)(a1[2] & 0xffff)), b2f((u16)(a1[2] >> 16)),
                        b2f((u16)(a1[3] & 0xffff)), b2f((u16)(a1[3] >> 16)));
    const u16* vb = qkv + rowbase + 512 + hh * 32 + ds;
    u32x4 b0 = *(const u32x4*)vb;
    u32x4 b1 = *(const u32x4*)(vb + 8);
    float4* dv = (float4*)&sV[wv][p][ds];
    dv[0] = make_float4(b2f((u16)(b0[0] & 0xffff)), b2f((u16)(b0[0] >> 16)),
                        b2f((u16)(b0[1] & 0xffff)), b2f((u16)(b0[1] >> 16)));
    dv[1] = make_float4(b2f((u16)(b0[2] & 0xffff)), b2f((u16)(b0[2] >> 16)),
                        b2f((u16)(b0[3] & 0xffff)), b2f((u16)(b0[3] >> 16)));
    dv[2] = make_float4(b2f((u16)(b1[0] & 0xffff)), b2f((u16)(b1[0] >> 16)),
                        b2f((u16)(b1[1] & 0xffff)), b2f((u16)(b1[1] >> 16)));
    dv[3] = make_float4(b2f((u16)(b1[2] & 0xffff)), b2f((u16)(b1[2] >> 16)),
                        b2f((u16)(b1[3] & 0xffff)), b2f((u16)(b1[3] >> 16)));
  }

  // ---- q row into registers, pre-scaled by 1/sqrt(32) ----
  float qr[32];
  {
    const u16* qb = qkv + rowbase + hh * 32;
    const float sc = 0.17677669529663687f;
#pragma unroll
    for (int j = 0; j < 2; j++) {
      u32x4 t0 = *(const u32x4*)(qb + j * 16);
      u32x4 t1 = *(const u32x4*)(qb + j * 16 + 8);
#pragma unroll
      for (int e = 0; e < 4; e++) {
        qr[j * 16 + 2 * e]     = b2f((u16)(t0[e] & 0xffff)) * sc;
        qr[j * 16 + 2 * e + 1] = b2f((u16)(t0[e] >> 16)) * sc;
        qr[j * 16 + 8 + 2 * e]     = b2f((u16)(t1[e] & 0xffff)) * sc;
        qr[j * 16 + 8 + 2 * e + 1] = b2f((u16)(t1[e] >> 16)) * sc;
      }
    }
  }
  __syncthreads();

  // ---- scores: this lane owns q-row p, k-positions [ds, ds+16) ----
  float s[16];
  {
    const int* rp = rel_pos + (((size_t)nw * 32 + p) * 32 + ds) * 3;
    const float* pm = pmask + ((size_t)nw * 32 + p) * 32 + ds;
#pragma unroll
    for (int i = 0; i < 16; i++) {
      int r0 = rp[3 * i], r1 = rp[3 * i + 1], r2 = rp[3 * i + 2];
      r0 = min(max(r0, -25), 25);
      r1 = min(max(r1, -25), 25);
      r2 = min(max(r2, -25), 25);
      s[i] = rpet[(r0 + 25) * 8 + hh] + rpet[(r1 + 76) * 8 + hh] +
             rpet[(r2 + 127) * 8 + hh] + pm[i];
    }
  }
#pragma unroll
  for (int i = 0; i < 16; i++) {
    float a = 0.f;
#pragma unroll
    for (int d4 = 0; d4 < 8; d4++) {
      float4 kv = *(const float4*)&sK[wv][ds + i][d4 * 4];
      a += qr[d4 * 4 + 0] * kv.x + qr[d4 * 4 + 1] * kv.y +
           qr[d4 * 4 + 2] * kv.z + qr[d4 * 4 + 3] * kv.w;
    }
    s[i] += a;
  }

  // ---- softmax over the full 32-wide row (pair of lanes) ----
  float mx = s[0];
#pragma unroll
  for (int i = 1; i < 16; i++) mx = fmaxf(mx, s[i]);
  mx = fmaxf(mx, __shfl_xor(mx, 1));
  float pr[16];
  float sum = 0.f;
#pragma unroll
  for (int i = 0; i < 16; i++) { pr[i] = __expf(s[i] - mx); sum += pr[i]; }
  sum += __shfl_xor(sum, 1);
  const float inv = 1.0f / sum;

  float pf[32];
#pragma unroll
  for (int i = 0; i < 16; i++) {
    const float mine = pr[i] * inv;
    const float other = __shfl_xor(mine, 1);
    pf[i]      = hlf ? other : mine;
    pf[16 + i] = hlf ? mine : other;
  }

  // ---- out[p][d] for d in [ds, ds+16) ----
  float4 o0 = make_float4(0, 0, 0, 0), o1 = o0, o2 = o0, o3 = o0;
#pragma unroll
  for (int k = 0; k < 32; k++) {
    const float pk = pf[k];
    const float4 v0 = *(const float4*)&sV[wv][k][ds + 0];
    const float4 v1 = *(const float4*)&sV[wv][k][ds + 4];
    const float4 v2 = *(const float4*)&sV[wv][k][ds + 8];
    const float4 v3 = *(const float4*)&sV[wv][k][ds + 12];
    o0.x += pk * v0.x; o0.y += pk * v0.y; o0.z += pk * v0.z; o0.w += pk * v0.w;
    o1.x += pk * v1.x; o1.y += pk * v1.y; o1.z += pk * v1.z; o1.w += pk * v1.w;
    o2.x += pk * v2.x; o2.y += pk * v2.y; o2.z += pk * v2.z; o2.w += pk * v2.w;
    o3.x += pk * v3.x; o3.y += pk * v3.y; o3.z += pk * v3.z; o3.w += pk * v3.w;
  }

  u16* ob = out + (size_t)(nw * 32 + p) * 256 + hh * 32 + ds;
  u32x4 w0, w1;
  w0[0] = (u32)f2b(o0.x) | ((u32)f2b(o0.y) << 16);
  w0[1] = (u32)f2b(o0.z) | ((u32)f2b(o0.w) << 16);
  w0[2] = (u32)f2b(o1.x) | ((u32)f2b(o1.y) << 16);
  w0[3] = (u32)f2b(o1.z) | ((u32)f2b(o1.w) << 16);
  w1[0] = (u32)f2b(o2.x) | ((u32)f2b(o2.y) << 16);
  w1[1] = (u32)f2b(o2.z) | ((u32)f2b(o2.w) << 16);
  w1[2] = (u32)f2b(o3.x) | ((u32)f2b(o3.y) << 16);
  w1[3] = (u32)f2b(o3.z) | ((u32)f2b(o3.w) << 16);
  *(u32x4*)ob = w0;
  *((u32x4*)ob + 1) = w1;
}

extern "C" void kernel_launch(void* const* d_in, const int* in_sizes, int n_in,
                              void* d_out, int out_size, void* d_ws, size_t ws_size,
                              hipStream_t stream) {
  const float* data   = (const float*)d_in[0];
  const int*   nbr    = (const int*)d_in[1];
  const int*   relpos = (const int*)d_in[2];
  const float* pmask  = (const float*)d_in[3];
  const float* w_cpe  = (const float*)d_in[4];
  const float* bn_g   = (const float*)d_in[5];
  const float* bn_b   = (const float*)d_in[6];
  const float* n1_g   = (const float*)d_in[7];
  const float* n1_b   = (const float*)d_in[8];
  const float* w_qkv  = (const float*)d_in[9];
  const float* b_qkv  = (const float*)d_in[10];
  const float* w_proj = (const float*)d_in[11];
  const float* b_proj = (const float*)d_in[12];
  const float* rpet   = (const float*)d_in[13];
  const float* n2_g   = (const float*)d_in[14];
  const float* n2_b   = (const float*)d_in[15];
  const float* w_fc1  = (const float*)d_in[16];
  const float* b_fc1  = (const float*)d_in[17];
  const float* w_fc2  = (const float*)d_in[18];
  const float* b_fc2  = (const float*)d_in[19];
  float* xout = (float*)d_out;  // residual stream x lives in d_out (f32)

  char* pw = (char*)d_ws;
  u16* buf1 = (u16*)pw; pw += (size_t)NPT * 1024 * 2;  // data_bf16 / qkv / ffn hidden
  u16* buf2 = (u16*)pw; pw += (size_t)NPT * 256 * 2;   // h / attn_out / h2
  u16* wqkvT = (u16*)pw; pw += 768 * 256 * 2;
  u16* wprojT = (u16*)pw; pw += 256 * 256 * 2;
  u16* wfc1T = (u16*)pw; pw += 1024 * 256 * 2;
  u16* wfc2T = (u16*)pw; pw += 256 * 1024 * 2;

  // prep: bf16 copy of data (for CPE gathers), transposed bf16 weights
  k_f2b<<<2048, 256, 0, stream>>>(data, buf1, NPT * 256 / 4);
  k_transpose_f2b<<<(256 * 768 + 255) / 256, 256, 0, stream>>>(w_qkv, wqkvT, 256, 768);
  k_transpose_f2b<<<(256 * 256 + 255) / 256, 256, 0, stream>>>(w_proj, wprojT, 256, 256);
  k_transpose_f2b<<<(256 * 1024 + 255) / 256, 256, 0, stream>>>(w_fc1, wfc1T, 256, 1024);
  k_transpose_f2b<<<(1024 * 256 + 255) / 256, 256, 0, stream>>>(w_fc2, wfc2T, 1024, 256);

  // CPE + residual + LN1:  x -> d_out(f32), h -> buf2(bf16)
  k_cpe_ln1<<<NPT, 256, 0, stream>>>(data, nbr, buf1, w_cpe, bn_g, bn_b, n1_g, n1_b,
                                     xout, buf2);
  // QKV = h @ w_qkv + b  -> buf1 (bf16, N x 768)
  k_gemm<256, 768, 0><<<dim3(6, 1024), 256, 0, stream>>>(buf2, wqkvT, b_qkv, buf1, nullptr);
  // attention -> buf2 (bf16, N x 256)
  k_attn<<<NWIN * 2, 256, 0, stream>>>(buf1, relpos, pmask, rpet, buf2);
  // x += attn_out @ w_proj + b
  k_gemm<256, 256, 1><<<dim3(2, 1024), 256, 0, stream>>>(buf2, wprojT, b_proj, nullptr, xout);
  // h2 = LN2(x) -> buf2
  k_ln2<<<NPT / 4, 256, 0, stream>>>(xout, n2_g, n2_b, buf2);
  // hidden = gelu(h2 @ w_fc1 + b) -> buf1 (bf16, N x 1024)
  k_gemm<256, 1024, 2><<<dim3(8, 1024), 256, 0, stream>>>(buf2, wfc1T, b_fc1, buf1, nullptr);
  // x += hidden @ w_fc2 + b   (final output in d_out)
  k_gemm<1024, 256, 1><<<dim3(2, 1024), 256, 0, stream>>>(buf1, wfc2T, b_fc2, nullptr, xout);
}

// Round 3
// 1072.533 us; speedup vs baseline: 1.2332x; 1.2332x over previous
//
#include <hip/hip_runtime.h>
#include <stdint.h>

// OctFormer block, MI355X gfx950.
// Pipeline: [f2b data] [transpose weights] -> CPE+LN1 -> QKV GEMM -> attn ->
//           proj GEMM(+resid) -> LN2 -> FC1 GEMM(+gelu) -> FC2 GEMM(+resid -> d_out)
// Residual stream x lives in d_out (f32). GEMMs: bf16 MFMA 16x16x32, 128x128 tile.
// Attn: 1 block/window, 8 waves = 8 heads, MFMA QK^T and PV (V transposed in LDS).

static constexpr int NPT   = 131072;  // points
static constexpr int CC    = 256;     // channels
static constexpr int NWIN  = 4096;    // windows
static constexpr int NHEAD = 8;

using u16 = unsigned short;
using u32 = unsigned int;

typedef __bf16 bf16x8 __attribute__((ext_vector_type(8)));
typedef float  f32x4  __attribute__((ext_vector_type(4)));
typedef u32    u32x4  __attribute__((ext_vector_type(4)));

__device__ __forceinline__ float b2f(u16 u) {
  union { float f; u32 i; } v; v.i = ((u32)u) << 16; return v.f;
}
__device__ __forceinline__ u16 f2b(float f) {  // RNE f32 -> bf16
  u32 x = __float_as_uint(f);
  return (u16)((x + 0x7fffu + ((x >> 16) & 1u)) >> 16);
}

__device__ __forceinline__ void gload_lds16(const void* g, void* l) {
  using gptr_t = const __attribute__((address_space(1))) uint32_t*;
  using lptr_t = __attribute__((address_space(3))) uint32_t*;
  __builtin_amdgcn_global_load_lds((gptr_t)(uintptr_t)g,
                                   (lptr_t)(uint32_t)(uintptr_t)l, 16, 0, 0);
}

// ---------------- f32 -> bf16 bulk convert ----------------
__global__ __launch_bounds__(256) void k_f2b(const float* __restrict__ in,
                                             u16* __restrict__ out, int n4) {
  for (int i = blockIdx.x * 256 + threadIdx.x; i < n4; i += gridDim.x * 256) {
    float4 v = ((const float4*)in)[i];
    ushort4 o;
    o.x = f2b(v.x); o.y = f2b(v.y); o.z = f2b(v.z); o.w = f2b(v.w);
    ((ushort4*)out)[i] = o;
  }
}

// ---------------- transpose + convert: out[c*R + r] = in[r*Cc + c] ----------------
__global__ __launch_bounds__(256) void k_transpose_f2b(const float* __restrict__ in,
                                                       u16* __restrict__ out, int R, int Cc) {
  int i = blockIdx.x * 256 + threadIdx.x;
  if (i >= R * Cc) return;
  int c = i / R, r = i - c * R;          // i = c*R + r : coalesced writes
  out[i] = f2b(in[r * Cc + c]);
}

// ---------------- CPE gather + residual + LN1 ----------------
__global__ __launch_bounds__(256) void k_cpe_ln1(
    const float* __restrict__ data, const int* __restrict__ nbr,
    const u16* __restrict__ datab, const float* __restrict__ w_cpe,
    const float* __restrict__ bn_g, const float* __restrict__ bn_b,
    const float* __restrict__ n1_g, const float* __restrict__ n1_b,
    float* __restrict__ xo, u16* __restrict__ ho) {
  const int n = blockIdx.x;
  const int c = threadIdx.x;
  const int* nb = nbr + n * 27;
  float acc = 0.f;
#pragma unroll
  for (int j = 0; j < 27; j++) {
    const int idx = nb[j];
    acc += b2f(datab[(size_t)idx * CC + c]) * w_cpe[j * CC + c];
  }
  const float xv = data[(size_t)n * CC + c] + acc * bn_g[c] + bn_b[c];
  xo[(size_t)n * CC + c] = xv;
  float s = xv, s2 = xv * xv;
#pragma unroll
  for (int m = 1; m <= 32; m <<= 1) { s += __shfl_xor(s, m); s2 += __shfl_xor(s2, m); }
  __shared__ float ps[4], ps2[4];
  const int wv = threadIdx.x >> 6;
  if ((threadIdx.x & 63) == 0) { ps[wv] = s; ps2[wv] = s2; }
  __syncthreads();
  s  = ps[0] + ps[1] + ps[2] + ps[3];
  s2 = ps2[0] + ps2[1] + ps2[2] + ps2[3];
  const float mean = s * (1.f / 256.f);
  const float var  = s2 * (1.f / 256.f) - mean * mean;
  const float inv  = rsqrtf(var + 1e-5f);
  ho[(size_t)n * CC + c] = f2b((xv - mean) * inv * n1_g[c] + n1_b[c]);
}

// ---------------- LN2 (wave per row) ----------------
__global__ __launch_bounds__(256) void k_ln2(const float* __restrict__ x,
                                             const float* __restrict__ g,
                                             const float* __restrict__ b,
                                             u16* __restrict__ h) {
  const int row = blockIdx.x * 4 + (threadIdx.x >> 6);
  const int l = threadIdx.x & 63;
  const float4 xv = ((const float4*)(x + (size_t)row * CC))[l];
  float s  = xv.x + xv.y + xv.z + xv.w;
  float s2 = xv.x * xv.x + xv.y * xv.y + xv.z * xv.z + xv.w * xv.w;
#pragma unroll
  for (int m = 1; m <= 32; m <<= 1) { s += __shfl_xor(s, m); s2 += __shfl_xor(s2, m); }
  const float mean = s * (1.f / 256.f);
  const float var  = s2 * (1.f / 256.f) - mean * mean;
  const float inv  = rsqrtf(var + 1e-5f);
  const int c = l * 4;
  ushort4 o;
  o.x = f2b((xv.x - mean) * inv * g[c + 0] + b[c + 0]);
  o.y = f2b((xv.y - mean) * inv * g[c + 1] + b[c + 1]);
  o.z = f2b((xv.z - mean) * inv * g[c + 2] + b[c + 2]);
  o.w = f2b((xv.w - mean) * inv * g[c + 3] + b[c + 3]);
  ((ushort4*)(h + (size_t)row * CC))[l] = o;
}

// ---------------- MFMA GEMM: C[M][ND] = A[M][KD] * Bt[ND][KD]^T ----------------
// EPI 0: out_bf16 = acc + bias
// EPI 1: out_f32 += acc + bias            (residual accumulate)
// EPI 2: out_bf16 = gelu_exact(acc + bias)
template <int KD, int ND, int EPI>
__global__ __launch_bounds__(256) void k_gemm(const u16* __restrict__ A,
                                              const u16* __restrict__ Bt,
                                              const float* __restrict__ bias,
                                              u16* __restrict__ outb,
                                              float* __restrict__ outf) {
  __shared__ __align__(16) u16 As[128 * 64];
  __shared__ __align__(16) u16 Bs[128 * 64];
  const int tid = threadIdx.x;
  const int lane = tid & 63;
  const int wv = tid >> 6;
  const int wm = (wv >> 1) * 64;
  const int wn = (wv & 1) * 64;
  const int l15 = lane & 15;
  const int lhi = lane >> 4;
  const int m0 = blockIdx.y * 128;
  const int n0 = blockIdx.x * 128;

  f32x4 acc[4][4] = {};

  for (int k0 = 0; k0 < KD; k0 += 64) {
#pragma unroll
    for (int i = 0; i < 4; i++) {
      const int off = i * 4096 + tid * 16;     // byte offset in 16KB tile
      const int row = off >> 7;                // 128B (=64 bf16) per row
      const int ke  = (off & 127) >> 1;        // element offset in K
      gload_lds16(A  + (size_t)(m0 + row) * KD + k0 + ke, (char*)As + off);
      gload_lds16(Bt + (size_t)(n0 + row) * KD + k0 + ke, (char*)Bs + off);
    }
    __syncthreads();
#pragma unroll
    for (int kk = 0; kk < 2; kk++) {
      bf16x8 fa[4], fb[4];
#pragma unroll
      for (int t = 0; t < 4; t++) {
        fa[t] = *(const bf16x8*)&As[(wm + t * 16 + l15) * 64 + kk * 32 + lhi * 8];
        fb[t] = *(const bf16x8*)&Bs[(wn + t * 16 + l15) * 64 + kk * 32 + lhi * 8];
      }
#pragma unroll
      for (int mi = 0; mi < 4; mi++)
#pragma unroll
        for (int ni = 0; ni < 4; ni++)
          acc[mi][ni] = __builtin_amdgcn_mfma_f32_16x16x32_bf16(fa[mi], fb[ni],
                                                                acc[mi][ni], 0, 0, 0);
    }
    __syncthreads();
  }

#pragma unroll
  for (int mi = 0; mi < 4; mi++) {
#pragma unroll
    for (int ni = 0; ni < 4; ni++) {
      const int col = n0 + wn + ni * 16 + l15;
      const float bc = bias[col];
#pragma unroll
      for (int r = 0; r < 4; r++) {
        const int row = m0 + wm + mi * 16 + lhi * 4 + r;
        const size_t o = (size_t)row * ND + col;
        float v = acc[mi][ni][r] + bc;
        if constexpr (EPI == 0) {
          outb[o] = f2b(v);
        } else if constexpr (EPI == 1) {
          outf[o] += v;
        } else {
          v = 0.5f * v * (1.0f + erff(v * 0.70710678118654752f));
          outb[o] = f2b(v);
        }
      }
    }
  }
}

// ---------------- windowed attention with RPE (MFMA version) ----------------
// 1 block = 1 window, 512 threads = 8 waves, wave w = head w.
// LDS: sQ/sK/sV per head [32 rows][40 u16] (80B padded rows, head stride 1288 u16),
// sT = rpe table transposed [8][153] f32. P reuses sQ[h]; O_lds reuses sK.
__global__ __launch_bounds__(512, 4) void k_attn(const u16* __restrict__ qkv,
                                                 const int* __restrict__ rel_pos,
                                                 const float* __restrict__ pmask,
                                                 const float* __restrict__ rpet,
                                                 u16* __restrict__ out) {
  constexpr int HS = 1288;                      // u16 per head region (2576 B)
  __shared__ __align__(16) u16 smem[24 * HS + 2448];
  u16* sQ = smem;
  u16* sK = smem + 8 * HS;                      // overlaid by O_lds [32][264] later
  u16* sV = smem + 16 * HS;                     // V^T per head: [d][p], rows 40 u16
  float* sT = (float*)(smem + 24 * HS);         // [8][153]

  const int tid = threadIdx.x;
  const int nw  = blockIdx.x;
  const int w32 = nw * 32;

  // ---- stage rpe table transposed: sT[h*153 + ix] = rpet[ix*8 + h] ----
  for (int i = tid; i < 1224; i += 512) {
    int h = i / 153, ix = i - h * 153;
    sT[i] = rpet[ix * 8 + h];
  }
  // ---- stage Q, K: 2048 16B chunks ----
#pragma unroll
  for (int j = 0; j < 4; j++) {
    int id  = j * 512 + tid;
    int mat = id >> 10;                         // 0 = Q, 1 = K (wave-uniform)
    int id1 = id & 1023;
    int h = id1 >> 7, q = (id1 >> 2) & 31, s = id1 & 3;
    u32x4 v = *(const u32x4*)(qkv + (size_t)(w32 + q) * 768 + mat * 256 + h * 32 + s * 8);
    u16* dst = (mat ? sK : sQ) + h * HS + q * 40 + s * 8;
    *(u32x4*)dst = v;
  }
  // ---- stage V transposed: VT[h][d&31][p] ----
#pragma unroll
  for (int j = 0; j < 2; j++) {
    int id = j * 512 + tid;
    int p = id >> 5, dc = id & 31;
    u32x4 v = *(const u32x4*)(qkv + (size_t)(w32 + p) * 768 + 512 + dc * 8);
    const u16* pv = (const u16*)&v;
#pragma unroll
    for (int jj = 0; jj < 8; jj++) {
      int d = dc * 8 + jj;
      sV[(d >> 5) * HS + (d & 31) * 40 + p] = pv[jj];
    }
  }
  __syncthreads();

  const int h = tid >> 6;
  const int lane = tid & 63;
  const int g = lane >> 4, c = lane & 15;
  const f32x4 zero = {0.f, 0.f, 0.f, 0.f};

  // ---- QK^T via MFMA: S[q][k], tiles (qt,kt) ----
  bf16x8 fq[2], fk[2];
#pragma unroll
  for (int t = 0; t < 2; t++) {
    fq[t] = *(const bf16x8*)&sQ[h * HS + (t * 16 + c) * 40 + g * 8];
    fk[t] = *(const bf16x8*)&sK[h * HS + (t * 16 + c) * 40 + g * 8];
  }
  f32x4 S[2][2];
#pragma unroll
  for (int qt = 0; qt < 2; qt++)
#pragma unroll
    for (int kt = 0; kt < 2; kt++)
      S[qt][kt] = __builtin_amdgcn_mfma_f32_16x16x32_bf16(fq[qt], fk[kt], zero, 0, 0, 0);

  // ---- bias (rpe + mask) + scale + softmax per q-row, write P to sQ[h] ----
  const float sc = 0.17677669529663687f;  // 32^-0.5
#pragma unroll
  for (int qt = 0; qt < 2; qt++) {
#pragma unroll
    for (int r = 0; r < 4; r++) {
      const int q = qt * 16 + g * 4 + r;
      const int* rp = rel_pos + ((size_t)(w32 + q) * 32) * 3;
      const float* pm = pmask + (size_t)(w32 + q) * 32;
      float v[2];
#pragma unroll
      for (int kt = 0; kt < 2; kt++) {
        const int k = kt * 16 + c;
        int r0 = rp[k * 3], r1 = rp[k * 3 + 1], r2 = rp[k * 3 + 2];
        r0 = min(max(r0, -25), 25);
        r1 = min(max(r1, -25), 25);
        r2 = min(max(r2, -25), 25);
        const float b = sT[h * 153 + 25 + r0] + sT[h * 153 + 76 + r1] +
                        sT[h * 153 + 127 + r2] + pm[k];
        v[kt] = S[qt][kt][r] * sc + b;
      }
      float m = fmaxf(v[0], v[1]);
#pragma unroll
      for (int d = 1; d <= 8; d <<= 1) m = fmaxf(m, __shfl_xor(m, d));
      const float e0 = __expf(v[0] - m);
      const float e1 = __expf(v[1] - m);
      float ssum = e0 + e1;
#pragma unroll
      for (int d = 1; d <= 8; d <<= 1) ssum += __shfl_xor(ssum, d);
      const float inv = 1.0f / ssum;
      sQ[h * HS + q * 40 + c]      = f2b(e0 * inv);
      sQ[h * HS + q * 40 + 16 + c] = f2b(e1 * inv);
    }
  }
  __builtin_amdgcn_sched_barrier(0);  // P writes stay before P-fragment reads

  // ---- PV via MFMA: O^T[d][q] = sum_k VT[d][k] * P[q][k] ----
  bf16x8 fp[2], fv[2];
#pragma unroll
  for (int t = 0; t < 2; t++) {
    fp[t] = *(const bf16x8*)&sQ[h * HS + (t * 16 + c) * 40 + g * 8];
    fv[t] = *(const bf16x8*)&sV[h * HS + (t * 16 + c) * 40 + g * 8];
  }
  f32x4 OT[2][2];
#pragma unroll
  for (int dt = 0; dt < 2; dt++)
#pragma unroll
    for (int qt = 0; qt < 2; qt++)
      OT[dt][qt] = __builtin_amdgcn_mfma_f32_16x16x32_bf16(fv[dt], fp[qt], zero, 0, 0, 0);

  __syncthreads();                     // all waves done reading K: reuse sK as O_lds
  u16* OL = sK;                        // [32 rows][264 u16] (528B padded rows)
#pragma unroll
  for (int dt = 0; dt < 2; dt++)
#pragma unroll
    for (int qt = 0; qt < 2; qt++)
#pragma unroll
      for (int r = 0; r < 4; r++) {
        const int d = dt * 16 + g * 4 + r, q = qt * 16 + c;
        OL[q * 264 + h * 32 + d] = f2b(OT[dt][qt][r]);
      }
  __syncthreads();

  // ---- cooperative coalesced store: 32 rows x 512B ----
  {
    const int q = tid >> 4, ch = tid & 15;
    u32x4 w0 = *(const u32x4*)&OL[q * 264 + ch * 16];
    u32x4 w1 = *(const u32x4*)&OL[q * 264 + ch * 16 + 8];
    u16* ob = out + (size_t)(w32 + q) * 256 + ch * 16;
    *(u32x4*)ob = w0;
    *((u32x4*)ob + 1) = w1;
  }
}

extern "C" void kernel_launch(void* const* d_in, const int* in_sizes, int n_in,
                              void* d_out, int out_size, void* d_ws, size_t ws_size,
                              hipStream_t stream) {
  const float* data   = (const float*)d_in[0];
  const int*   nbr    = (const int*)d_in[1];
  const int*   relpos = (const int*)d_in[2];
  const float* pmask  = (const float*)d_in[3];
  const float* w_cpe  = (const float*)d_in[4];
  const float* bn_g   = (const float*)d_in[5];
  const float* bn_b   = (const float*)d_in[6];
  const float* n1_g   = (const float*)d_in[7];
  const float* n1_b   = (const float*)d_in[8];
  const float* w_qkv  = (const float*)d_in[9];
  const float* b_qkv  = (const float*)d_in[10];
  const float* w_proj = (const float*)d_in[11];
  const float* b_proj = (const float*)d_in[12];
  const float* rpet   = (const float*)d_in[13];
  const float* n2_g   = (const float*)d_in[14];
  const float* n2_b   = (const float*)d_in[15];
  const float* w_fc1  = (const float*)d_in[16];
  const float* b_fc1  = (const float*)d_in[17];
  const float* w_fc2  = (const float*)d_in[18];
  const float* b_fc2  = (const float*)d_in[19];
  float* xout = (float*)d_out;  // residual stream x lives in d_out (f32)

  char* pw = (char*)d_ws;
  u16* buf1 = (u16*)pw; pw += (size_t)NPT * 1024 * 2;  // data_bf16 / qkv / ffn hidden
  u16* buf2 = (u16*)pw; pw += (size_t)NPT * 256 * 2;   // h / attn_out / h2
  u16* wqkvT = (u16*)pw; pw += 768 * 256 * 2;
  u16* wprojT = (u16*)pw; pw += 256 * 256 * 2;
  u16* wfc1T = (u16*)pw; pw += 1024 * 256 * 2;
  u16* wfc2T = (u16*)pw; pw += 256 * 1024 * 2;

  // prep: bf16 copy of data (for CPE gathers), transposed bf16 weights
  k_f2b<<<2048, 256, 0, stream>>>(data, buf1, NPT * 256 / 4);
  k_transpose_f2b<<<(256 * 768 + 255) / 256, 256, 0, stream>>>(w_qkv, wqkvT, 256, 768);
  k_transpose_f2b<<<(256 * 256 + 255) / 256, 256, 0, stream>>>(w_proj, wprojT, 256, 256);
  k_transpose_f2b<<<(256 * 1024 + 255) / 256, 256, 0, stream>>>(w_fc1, wfc1T, 256, 1024);
  k_transpose_f2b<<<(1024 * 256 + 255) / 256, 256, 0, stream>>>(w_fc2, wfc2T, 1024, 256);

  // CPE + residual + LN1:  x -> d_out(f32), h -> buf2(bf16)
  k_cpe_ln1<<<NPT, 256, 0, stream>>>(data, nbr, buf1, w_cpe, bn_g, bn_b, n1_g, n1_b,
                                     xout, buf2);
  // QKV = h @ w_qkv + b  -> buf1 (bf16, N x 768)
  k_gemm<256, 768, 0><<<dim3(6, 1024), 256, 0, stream>>>(buf2, wqkvT, b_qkv, buf1, nullptr);
  // attention -> buf2 (bf16, N x 256)
  k_attn<<<NWIN, 512, 0, stream>>>(buf1, relpos, pmask, rpet, buf2);
  // x += attn_out @ w_proj + b
  k_gemm<256, 256, 1><<<dim3(2, 1024), 256, 0, stream>>>(buf2, wprojT, b_proj, nullptr, xout);
  // h2 = LN2(x) -> buf2
  k_ln2<<<NPT / 4, 256, 0, stream>>>(xout, n2_g, n2_b, buf2);
  // hidden = gelu(h2 @ w_fc1 + b) -> buf1 (bf16, N x 1024)
  k_gemm<256, 1024, 2><<<dim3(8, 1024), 256, 0, stream>>>(buf2, wfc1T, b_fc1, buf1, nullptr);
  // x += hidden @ w_fc2 + b   (final output in d_out)
  k_gemm<1024, 256, 1><<<dim3(2, 1024), 256, 0, stream>>>(buf1, wfc2T, b_fc2, nullptr, xout);
}

// Round 4
// 1027.979 us; speedup vs baseline: 1.2866x; 1.0433x over previous
//
#include <hip/hip_runtime.h>
#include <stdint.h>

// OctFormer block, MI355X gfx950.
// Pipeline: [f2b data] [transpose weights] -> CPE+LN1 -> QKV GEMM -> attn ->
//           proj GEMM(+resid) -> LN2 -> FC1 GEMM(+gelu) -> FC2 GEMM(+resid -> d_out)
// Residual stream x lives in d_out (f32). GEMMs: bf16 MFMA 16x16x32, 128x128 tile.
// Attn: 1 block/window, 8 waves = 8 heads, MFMA QK^T and PV (V transposed in LDS).
// CPE: 1 wave/point, full-row dwordx2 gathers via readlane-broadcast SGPR base.

static constexpr int NPT   = 131072;  // points
static constexpr int CC    = 256;     // channels
static constexpr int NWIN  = 4096;    // windows
static constexpr int NHEAD = 8;

using u16 = unsigned short;
using u32 = unsigned int;

typedef __bf16 bf16x8 __attribute__((ext_vector_type(8)));
typedef float  f32x4  __attribute__((ext_vector_type(4)));
typedef u32    u32x4  __attribute__((ext_vector_type(4)));
typedef u32    u32x2  __attribute__((ext_vector_type(2)));

__device__ __forceinline__ float b2f(u16 u) {
  union { float f; u32 i; } v; v.i = ((u32)u) << 16; return v.f;
}
__device__ __forceinline__ u16 f2b(float f) {  // RNE f32 -> bf16
  u32 x = __float_as_uint(f);
  return (u16)((x + 0x7fffu + ((x >> 16) & 1u)) >> 16);
}

__device__ __forceinline__ void gload_lds16(const void* g, void* l) {
  using gptr_t = const __attribute__((address_space(1))) uint32_t*;
  using lptr_t = __attribute__((address_space(3))) uint32_t*;
  __builtin_amdgcn_global_load_lds((gptr_t)(uintptr_t)g,
                                   (lptr_t)(uint32_t)(uintptr_t)l, 16, 0, 0);
}

// ---------------- f32 -> bf16 bulk convert ----------------
__global__ __launch_bounds__(256) void k_f2b(const float* __restrict__ in,
                                             u16* __restrict__ out, int n4) {
  for (int i = blockIdx.x * 256 + threadIdx.x; i < n4; i += gridDim.x * 256) {
    float4 v = ((const float4*)in)[i];
    ushort4 o;
    o.x = f2b(v.x); o.y = f2b(v.y); o.z = f2b(v.z); o.w = f2b(v.w);
    ((ushort4*)out)[i] = o;
  }
}

// ---------------- transpose + convert: out[c*R + r] = in[r*Cc + c] ----------------
__global__ __launch_bounds__(256) void k_transpose_f2b(const float* __restrict__ in,
                                                       u16* __restrict__ out, int R, int Cc) {
  int i = blockIdx.x * 256 + threadIdx.x;
  if (i >= R * Cc) return;
  int c = i / R, r = i - c * R;          // i = c*R + r : coalesced writes
  out[i] = f2b(in[r * Cc + c]);
}

// ---------------- CPE gather + residual + LN1 (wave per point) ----------------
// Wave handles point n; lane owns channels [4*lane, 4*lane+4). Each neighbor row
// (512 B bf16) is fetched by the whole wave as one global_load_dwordx2 from an
// SGPR (readlane-broadcast) base -> 4 cache lines in flight per instruction.
__global__ __launch_bounds__(256) void k_cpe_ln1(
    const float* __restrict__ data, const int* __restrict__ nbr,
    const u16* __restrict__ datab, const float* __restrict__ w_cpe,
    const float* __restrict__ bn_g, const float* __restrict__ bn_b,
    const float* __restrict__ n1_g, const float* __restrict__ n1_b,
    float* __restrict__ xo, u16* __restrict__ ho) {
  const int wv   = threadIdx.x >> 6;
  const int lane = threadIdx.x & 63;
  const int n    = blockIdx.x * 4 + wv;
  const int c0   = lane * 4;

  int myidx = 0;
  if (lane < 27) myidx = nbr[n * 27 + lane];

  float a0 = 0.f, a1 = 0.f, a2 = 0.f, a3 = 0.f;
#pragma unroll
  for (int j = 0; j < 27; j++) {
    const int idx = __builtin_amdgcn_readlane(myidx, j);
    const u32x2 d = *(const u32x2*)(datab + (size_t)idx * CC + c0);
    const float4 wj = *(const float4*)(w_cpe + j * CC + c0);
    a0 += b2f((u16)(d[0] & 0xffff)) * wj.x;
    a1 += b2f((u16)(d[0] >> 16))    * wj.y;
    a2 += b2f((u16)(d[1] & 0xffff)) * wj.z;
    a3 += b2f((u16)(d[1] >> 16))    * wj.w;
  }

  const float4 dv = *(const float4*)(data + (size_t)n * CC + c0);
  const float4 g4 = *(const float4*)(bn_g + c0);
  const float4 b4 = *(const float4*)(bn_b + c0);
  float x0 = dv.x + a0 * g4.x + b4.x;
  float x1 = dv.y + a1 * g4.y + b4.y;
  float x2 = dv.z + a2 * g4.z + b4.z;
  float x3 = dv.w + a3 * g4.w + b4.w;
  *(float4*)(xo + (size_t)n * CC + c0) = make_float4(x0, x1, x2, x3);

  float s  = x0 + x1 + x2 + x3;
  float s2 = x0 * x0 + x1 * x1 + x2 * x2 + x3 * x3;
#pragma unroll
  for (int m = 1; m <= 32; m <<= 1) { s += __shfl_xor(s, m); s2 += __shfl_xor(s2, m); }
  const float mean = s * (1.f / 256.f);
  const float var  = s2 * (1.f / 256.f) - mean * mean;
  const float inv  = rsqrtf(var + 1e-5f);

  const float4 ng = *(const float4*)(n1_g + c0);
  const float4 nb4 = *(const float4*)(n1_b + c0);
  u32x2 o;
  o[0] = (u32)f2b((x0 - mean) * inv * ng.x + nb4.x) |
         ((u32)f2b((x1 - mean) * inv * ng.y + nb4.y) << 16);
  o[1] = (u32)f2b((x2 - mean) * inv * ng.z + nb4.z) |
         ((u32)f2b((x3 - mean) * inv * ng.w + nb4.w) << 16);
  *(u32x2*)(ho + (size_t)n * CC + c0) = o;
}

// ---------------- LN2 (wave per row) ----------------
__global__ __launch_bounds__(256) void k_ln2(const float* __restrict__ x,
                                             const float* __restrict__ g,
                                             const float* __restrict__ b,
                                             u16* __restrict__ h) {
  const int row = blockIdx.x * 4 + (threadIdx.x >> 6);
  const int l = threadIdx.x & 63;
  const float4 xv = ((const float4*)(x + (size_t)row * CC))[l];
  float s  = xv.x + xv.y + xv.z + xv.w;
  float s2 = xv.x * xv.x + xv.y * xv.y + xv.z * xv.z + xv.w * xv.w;
#pragma unroll
  for (int m = 1; m <= 32; m <<= 1) { s += __shfl_xor(s, m); s2 += __shfl_xor(s2, m); }
  const float mean = s * (1.f / 256.f);
  const float var  = s2 * (1.f / 256.f) - mean * mean;
  const float inv  = rsqrtf(var + 1e-5f);
  const int c = l * 4;
  ushort4 o;
  o.x = f2b((xv.x - mean) * inv * g[c + 0] + b[c + 0]);
  o.y = f2b((xv.y - mean) * inv * g[c + 1] + b[c + 1]);
  o.z = f2b((xv.z - mean) * inv * g[c + 2] + b[c + 2]);
  o.w = f2b((xv.w - mean) * inv * g[c + 3] + b[c + 3]);
  ((ushort4*)(h + (size_t)row * CC))[l] = o;
}

// ---------------- MFMA GEMM: C[M][ND] = A[M][KD] * Bt[ND][KD]^T ----------------
// EPI 0: out_bf16 = acc + bias
// EPI 1: out_f32 += acc + bias            (residual accumulate)
// EPI 2: out_bf16 = gelu_exact(acc + bias)
template <int KD, int ND, int EPI>
__global__ __launch_bounds__(256) void k_gemm(const u16* __restrict__ A,
                                              const u16* __restrict__ Bt,
                                              const float* __restrict__ bias,
                                              u16* __restrict__ outb,
                                              float* __restrict__ outf) {
  __shared__ __align__(16) u16 As[128 * 64];
  __shared__ __align__(16) u16 Bs[128 * 64];
  const int tid = threadIdx.x;
  const int lane = tid & 63;
  const int wv = tid >> 6;
  const int wm = (wv >> 1) * 64;
  const int wn = (wv & 1) * 64;
  const int l15 = lane & 15;
  const int lhi = lane >> 4;
  const int m0 = blockIdx.y * 128;
  const int n0 = blockIdx.x * 128;

  f32x4 acc[4][4] = {};

  for (int k0 = 0; k0 < KD; k0 += 64) {
#pragma unroll
    for (int i = 0; i < 4; i++) {
      const int off = i * 4096 + tid * 16;     // byte offset in 16KB tile
      const int row = off >> 7;                // 128B (=64 bf16) per row
      const int ke  = (off & 127) >> 1;        // element offset in K
      gload_lds16(A  + (size_t)(m0 + row) * KD + k0 + ke, (char*)As + off);
      gload_lds16(Bt + (size_t)(n0 + row) * KD + k0 + ke, (char*)Bs + off);
    }
    __syncthreads();
#pragma unroll
    for (int kk = 0; kk < 2; kk++) {
      bf16x8 fa[4], fb[4];
#pragma unroll
      for (int t = 0; t < 4; t++) {
        fa[t] = *(const bf16x8*)&As[(wm + t * 16 + l15) * 64 + kk * 32 + lhi * 8];
        fb[t] = *(const bf16x8*)&Bs[(wn + t * 16 + l15) * 64 + kk * 32 + lhi * 8];
      }
#pragma unroll
      for (int mi = 0; mi < 4; mi++)
#pragma unroll
        for (int ni = 0; ni < 4; ni++)
          acc[mi][ni] = __builtin_amdgcn_mfma_f32_16x16x32_bf16(fa[mi], fb[ni],
                                                                acc[mi][ni], 0, 0, 0);
    }
    __syncthreads();
  }

#pragma unroll
  for (int mi = 0; mi < 4; mi++) {
#pragma unroll
    for (int ni = 0; ni < 4; ni++) {
      const int col = n0 + wn + ni * 16 + l15;
      const float bc = bias[col];
#pragma unroll
      for (int r = 0; r < 4; r++) {
        const int row = m0 + wm + mi * 16 + lhi * 4 + r;
        const size_t o = (size_t)row * ND + col;
        float v = acc[mi][ni][r] + bc;
        if constexpr (EPI == 0) {
          outb[o] = f2b(v);
        } else if constexpr (EPI == 1) {
          outf[o] += v;
        } else {
          v = 0.5f * v * (1.0f + erff(v * 0.70710678118654752f));
          outb[o] = f2b(v);
        }
      }
    }
  }
}

// ---------------- windowed attention with RPE (MFMA version) ----------------
// 1 block = 1 window, 512 threads = 8 waves, wave w = head w.
// LDS: sQ/sK/sV per head [32 rows][40 u16] (80B padded rows, head stride 1288 u16),
// sT = rpe table transposed [8][153] f32. P reuses sQ[h]; O_lds reuses sK.
__global__ __launch_bounds__(512, 4) void k_attn(const u16* __restrict__ qkv,
                                                 const int* __restrict__ rel_pos,
                                                 const float* __restrict__ pmask,
                                                 const float* __restrict__ rpet,
                                                 u16* __restrict__ out) {
  constexpr int HS = 1288;                      // u16 per head region (2576 B)
  __shared__ __align__(16) u16 smem[24 * HS + 2448];
  u16* sQ = smem;
  u16* sK = smem + 8 * HS;                      // overlaid by O_lds [32][264] later
  u16* sV = smem + 16 * HS;                     // V^T per head: [d][p], rows 40 u16
  float* sT = (float*)(smem + 24 * HS);         // [8][153]

  const int tid = threadIdx.x;
  const int nw  = blockIdx.x;
  const int w32 = nw * 32;

  // ---- stage rpe table transposed: sT[h*153 + ix] = rpet[ix*8 + h] ----
  for (int i = tid; i < 1224; i += 512) {
    int h = i / 153, ix = i - h * 153;
    sT[i] = rpet[ix * 8 + h];
  }
  // ---- stage Q, K: 2048 16B chunks ----
#pragma unroll
  for (int j = 0; j < 4; j++) {
    int id  = j * 512 + tid;
    int mat = id >> 10;                         // 0 = Q, 1 = K (wave-uniform)
    int id1 = id & 1023;
    int h = id1 >> 7, q = (id1 >> 2) & 31, s = id1 & 3;
    u32x4 v = *(const u32x4*)(qkv + (size_t)(w32 + q) * 768 + mat * 256 + h * 32 + s * 8);
    u16* dst = (mat ? sK : sQ) + h * HS + q * 40 + s * 8;
    *(u32x4*)dst = v;
  }
  // ---- stage V transposed: VT[h][d&31][p] ----
#pragma unroll
  for (int j = 0; j < 2; j++) {
    int id = j * 512 + tid;
    int p = id >> 5, dc = id & 31;
    u32x4 v = *(const u32x4*)(qkv + (size_t)(w32 + p) * 768 + 512 + dc * 8);
    const u16* pv = (const u16*)&v;
#pragma unroll
    for (int jj = 0; jj < 8; jj++) {
      int d = dc * 8 + jj;
      sV[(d >> 5) * HS + (d & 31) * 40 + p] = pv[jj];
    }
  }
  __syncthreads();

  const int h = tid >> 6;
  const int lane = tid & 63;
  const int g = lane >> 4, c = lane & 15;
  const f32x4 zero = {0.f, 0.f, 0.f, 0.f};

  // ---- QK^T via MFMA: S[q][k], tiles (qt,kt) ----
  bf16x8 fq[2], fk[2];
#pragma unroll
  for (int t = 0; t < 2; t++) {
    fq[t] = *(const bf16x8*)&sQ[h * HS + (t * 16 + c) * 40 + g * 8];
    fk[t] = *(const bf16x8*)&sK[h * HS + (t * 16 + c) * 40 + g * 8];
  }
  f32x4 S[2][2];
#pragma unroll
  for (int qt = 0; qt < 2; qt++)
#pragma unroll
    for (int kt = 0; kt < 2; kt++)
      S[qt][kt] = __builtin_amdgcn_mfma_f32_16x16x32_bf16(fq[qt], fk[kt], zero, 0, 0, 0);

  // ---- bias (rpe + mask) + scale + softmax per q-row, write P to sQ[h] ----
  const float sc = 0.17677669529663687f;  // 32^-0.5
#pragma unroll
  for (int qt = 0; qt < 2; qt++) {
#pragma unroll
    for (int r = 0; r < 4; r++) {
      const int q = qt * 16 + g * 4 + r;
      const int* rp = rel_pos + ((size_t)(w32 + q) * 32) * 3;
      const float* pm = pmask + (size_t)(w32 + q) * 32;
      float v[2];
#pragma unroll
      for (int kt = 0; kt < 2; kt++) {
        const int k = kt * 16 + c;
        int r0 = rp[k * 3], r1 = rp[k * 3 + 1], r2 = rp[k * 3 + 2];
        r0 = min(max(r0, -25), 25);
        r1 = min(max(r1, -25), 25);
        r2 = min(max(r2, -25), 25);
        const float b = sT[h * 153 + 25 + r0] + sT[h * 153 + 76 + r1] +
                        sT[h * 153 + 127 + r2] + pm[k];
        v[kt] = S[qt][kt][r] * sc + b;
      }
      float m = fmaxf(v[0], v[1]);
#pragma unroll
      for (int d = 1; d <= 8; d <<= 1) m = fmaxf(m, __shfl_xor(m, d));
      const float e0 = __expf(v[0] - m);
      const float e1 = __expf(v[1] - m);
      float ssum = e0 + e1;
#pragma unroll
      for (int d = 1; d <= 8; d <<= 1) ssum += __shfl_xor(ssum, d);
      const float inv = 1.0f / ssum;
      sQ[h * HS + q * 40 + c]      = f2b(e0 * inv);
      sQ[h * HS + q * 40 + 16 + c] = f2b(e1 * inv);
    }
  }
  __builtin_amdgcn_sched_barrier(0);  // P writes stay before P-fragment reads

  // ---- PV via MFMA: O^T[d][q] = sum_k VT[d][k] * P[q][k] ----
  bf16x8 fp[2], fv[2];
#pragma unroll
  for (int t = 0; t < 2; t++) {
    fp[t] = *(const bf16x8*)&sQ[h * HS + (t * 16 + c) * 40 + g * 8];
    fv[t] = *(const bf16x8*)&sV[h * HS + (t * 16 + c) * 40 + g * 8];
  }
  f32x4 OT[2][2];
#pragma unroll
  for (int dt = 0; dt < 2; dt++)
#pragma unroll
    for (int qt = 0; qt < 2; qt++)
      OT[dt][qt] = __builtin_amdgcn_mfma_f32_16x16x32_bf16(fv[dt], fp[qt], zero, 0, 0, 0);

  __syncthreads();                     // all waves done reading K: reuse sK as O_lds
  u16* OL = sK;                        // [32 rows][264 u16] (528B padded rows)
#pragma unroll
  for (int dt = 0; dt < 2; dt++)
#pragma unroll
    for (int qt = 0; qt < 2; qt++)
#pragma unroll
      for (int r = 0; r < 4; r++) {
        const int d = dt * 16 + g * 4 + r, q = qt * 16 + c;
        OL[q * 264 + h * 32 + d] = f2b(OT[dt][qt][r]);
      }
  __syncthreads();

  // ---- cooperative coalesced store: 32 rows x 512B ----
  {
    const int q = tid >> 4, ch = tid & 15;
    u32x4 w0 = *(const u32x4*)&OL[q * 264 + ch * 16];
    u32x4 w1 = *(const u32x4*)&OL[q * 264 + ch * 16 + 8];
    u16* ob = out + (size_t)(w32 + q) * 256 + ch * 16;
    *(u32x4*)ob = w0;
    *((u32x4*)ob + 1) = w1;
  }
}

extern "C" void kernel_launch(void* const* d_in, const int* in_sizes, int n_in,
                              void* d_out, int out_size, void* d_ws, size_t ws_size,
                              hipStream_t stream) {
  const float* data   = (const float*)d_in[0];
  const int*   nbr    = (const int*)d_in[1];
  const int*   relpos = (const int*)d_in[2];
  const float* pmask  = (const float*)d_in[3];
  const float* w_cpe  = (const float*)d_in[4];
  const float* bn_g   = (const float*)d_in[5];
  const float* bn_b   = (const float*)d_in[6];
  const float* n1_g   = (const float*)d_in[7];
  const float* n1_b   = (const float*)d_in[8];
  const float* w_qkv  = (const float*)d_in[9];
  const float* b_qkv  = (const float*)d_in[10];
  const float* w_proj = (const float*)d_in[11];
  const float* b_proj = (const float*)d_in[12];
  const float* rpet   = (const float*)d_in[13];
  const float* n2_g   = (const float*)d_in[14];
  const float* n2_b   = (const float*)d_in[15];
  const float* w_fc1  = (const float*)d_in[16];
  const float* b_fc1  = (const float*)d_in[17];
  const float* w_fc2  = (const float*)d_in[18];
  const float* b_fc2  = (const float*)d_in[19];
  float* xout = (float*)d_out;  // residual stream x lives in d_out (f32)

  char* pw = (char*)d_ws;
  u16* buf1 = (u16*)pw; pw += (size_t)NPT * 1024 * 2;  // data_bf16 / qkv / ffn hidden
  u16* buf2 = (u16*)pw; pw += (size_t)NPT * 256 * 2;   // h / attn_out / h2
  u16* wqkvT = (u16*)pw; pw += 768 * 256 * 2;
  u16* wprojT = (u16*)pw; pw += 256 * 256 * 2;
  u16* wfc1T = (u16*)pw; pw += 1024 * 256 * 2;
  u16* wfc2T = (u16*)pw; pw += 256 * 1024 * 2;

  // prep: bf16 copy of data (for CPE gathers), transposed bf16 weights
  k_f2b<<<2048, 256, 0, stream>>>(data, buf1, NPT * 256 / 4);
  k_transpose_f2b<<<(256 * 768 + 255) / 256, 256, 0, stream>>>(w_qkv, wqkvT, 256, 768);
  k_transpose_f2b<<<(256 * 256 + 255) / 256, 256, 0, stream>>>(w_proj, wprojT, 256, 256);
  k_transpose_f2b<<<(256 * 1024 + 255) / 256, 256, 0, stream>>>(w_fc1, wfc1T, 256, 1024);
  k_transpose_f2b<<<(1024 * 256 + 255) / 256, 256, 0, stream>>>(w_fc2, wfc2T, 1024, 256);

  // CPE + residual + LN1:  x -> d_out(f32), h -> buf2(bf16)
  k_cpe_ln1<<<NPT / 4, 256, 0, stream>>>(data, nbr, buf1, w_cpe, bn_g, bn_b, n1_g, n1_b,
                                         xout, buf2);
  // QKV = h @ w_qkv + b  -> buf1 (bf16, N x 768)
  k_gemm<256, 768, 0><<<dim3(6, 1024), 256, 0, stream>>>(buf2, wqkvT, b_qkv, buf1, nullptr);
  // attention -> buf2 (bf16, N x 256)
  k_attn<<<NWIN, 512, 0, stream>>>(buf1, relpos, pmask, rpet, buf2);
  // x += attn_out @ w_proj + b
  k_gemm<256, 256, 1><<<dim3(2, 1024), 256, 0, stream>>>(buf2, wprojT, b_proj, nullptr, xout);
  // h2 = LN2(x) -> buf2
  k_ln2<<<NPT / 4, 256, 0, stream>>>(xout, n2_g, n2_b, buf2);
  // hidden = gelu(h2 @ w_fc1 + b) -> buf1 (bf16, N x 1024)
  k_gemm<256, 1024, 2><<<dim3(8, 1024), 256, 0, stream>>>(buf2, wfc1T, b_fc1, buf1, nullptr);
  // x += hidden @ w_fc2 + b   (final output in d_out)
  k_gemm<1024, 256, 1><<<dim3(2, 1024), 256, 0, stream>>>(buf1, wfc2T, b_fc2, nullptr, xout);
}

// Round 7
// 956.867 us; speedup vs baseline: 1.3823x; 1.0743x over previous
//
#include <hip/hip_runtime.h>
#include <stdint.h>

// OctFormer block, MI355X gfx950.
// Pipeline: [fp8 data copy] [transpose weights] -> CPE+LN1 -> QKV GEMM -> attn ->
//           proj GEMM(+resid) -> LN2 -> FC1 GEMM(+gelu) -> FC2 GEMM(+resid -> d_out)
// Residual stream x lives in d_out (f32). GEMMs: bf16 MFMA 16x16x32, 128x128 tile.
// Attn: 1 block/window, 8 waves = 8 heads, MFMA QK^T and PV (V transposed in LDS).
// CPE: 1 wave/point, fp8-e4m3 gather rows (256 B) via readlane-broadcast base.

static constexpr int NPT   = 131072;  // points
static constexpr int CC    = 256;     // channels
static constexpr int NWIN  = 4096;    // windows
static constexpr int NHEAD = 8;

using u16 = unsigned short;
using u32 = unsigned int;
using u8  = unsigned char;

typedef __bf16 bf16x8 __attribute__((ext_vector_type(8)));
typedef float  f32x4  __attribute__((ext_vector_type(4)));
typedef u32    u32x4  __attribute__((ext_vector_type(4)));
typedef u32    u32x2  __attribute__((ext_vector_type(2)));

__device__ __forceinline__ float b2f(u16 u) {
  union { float f; u32 i; } v; v.i = ((u32)u) << 16; return v.f;
}
__device__ __forceinline__ u16 f2b(float f) {  // RNE f32 -> bf16
  u32 x = __float_as_uint(f);
  return (u16)((x + 0x7fffu + ((x >> 16) & 1u)) >> 16);
}

// ---- OCP e4m3fn encode (RNE). Inputs here are |x| <= ~6, no saturation path.
__device__ __forceinline__ u8 f2fp8(float f) {
  const u32 s = (__float_as_uint(f) >> 24) & 0x80u;
  float a = fabsf(f);
  if (a >= 0.015625f) {                       // normal range
    u32 b = __float_as_uint(a);
    u32 rb = b + 0x7FFFFu + ((b >> 20) & 1u); // RNE on 3 mantissa bits
    u32 E = (rb >> 23) - 120u;                // exp bias 7
    return (u8)(s | (E << 3) | ((rb >> 20) & 7u));
  }
  int k = (int)rintf(a * 512.0f);             // denormal: multiples of 2^-9
  return (u8)(s | (u32)k);
}

// ---- OCP e4m3fn decode: byte J (compile-time) of dword d.
template <int J>
__device__ __forceinline__ float fp82f(u32 d) {
#if defined(__has_builtin)
#if __has_builtin(__builtin_amdgcn_cvt_f32_fp8)
  return __builtin_amdgcn_cvt_f32_fp8(d, J);
#else
  const u32 u = (d >> (8 * J)) & 0xFFu;
  const u32 e = (u >> 3) & 15u, m = u & 7u;
  float v = e ? __uint_as_float(((e + 120u) << 23) | (m << 20))
              : (float)m * 0.001953125f;
  return (u & 0x80u) ? -v : v;
#endif
#else
  const u32 u = (d >> (8 * J)) & 0xFFu;
  const u32 e = (u >> 3) & 15u, m = u & 7u;
  float v = e ? __uint_as_float(((e + 120u) << 23) | (m << 20))
              : (float)m * 0.001953125f;
  return (u & 0x80u) ? -v : v;
#endif
}

__device__ __forceinline__ void gload_lds16(const void* g, void* l) {
  using gptr_t = const __attribute__((address_space(1))) uint32_t*;
  using lptr_t = __attribute__((address_space(3))) uint32_t*;
  __builtin_amdgcn_global_load_lds((gptr_t)(uintptr_t)g,
                                   (lptr_t)(uint32_t)(uintptr_t)l, 16, 0, 0);
}

// ---------------- f32 -> fp8 e4m3 bulk convert ----------------
__global__ __launch_bounds__(256) void k_f2b8(const float* __restrict__ in,
                                              u8* __restrict__ out, int n4) {
  for (int i = blockIdx.x * 256 + threadIdx.x; i < n4; i += gridDim.x * 256) {
    float4 v = ((const float4*)in)[i];
    u32 o = (u32)f2fp8(v.x) | ((u32)f2fp8(v.y) << 8) |
            ((u32)f2fp8(v.z) << 16) | ((u32)f2fp8(v.w) << 24);
    ((u32*)out)[i] = o;
  }
}

// ---------------- transpose + convert: out[c*R + r] = in[r*Cc + c] ----------------
__global__ __launch_bounds__(256) void k_transpose_f2b(const float* __restrict__ in,
                                                       u16* __restrict__ out, int R, int Cc) {
  int i = blockIdx.x * 256 + threadIdx.x;
  if (i >= R * Cc) return;
  int c = i / R, r = i - c * R;          // i = c*R + r : coalesced writes
  out[i] = f2b(in[r * Cc + c]);
}

// ---------------- CPE gather + residual + LN1 (wave per point, fp8 rows) -------
// Wave handles point n; lane owns channels [4*lane, 4*lane+4). Each neighbor row
// (256 B fp8) is fetched by the whole wave as one global_load_dword from an
// SGPR (readlane-broadcast) base.
__global__ __launch_bounds__(256) void k_cpe_ln1(
    const float* __restrict__ data, const int* __restrict__ nbr,
    const u8* __restrict__ datab, const float* __restrict__ w_cpe,
    const float* __restrict__ bn_g, const float* __restrict__ bn_b,
    const float* __restrict__ n1_g, const float* __restrict__ n1_b,
    float* __restrict__ xo, u16* __restrict__ ho) {
  const int wv   = threadIdx.x >> 6;
  const int lane = threadIdx.x & 63;
  const int n    = blockIdx.x * 4 + wv;
  const int c0   = lane * 4;

  int myidx = 0;
  if (lane < 27) myidx = nbr[n * 27 + lane];

  float a0 = 0.f, a1 = 0.f, a2 = 0.f, a3 = 0.f;
#pragma unroll
  for (int j = 0; j < 27; j++) {
    const int idx = __builtin_amdgcn_readlane(myidx, j);
    const u32 d = *(const u32*)(datab + (size_t)idx * CC + c0);
    const float4 wj = *(const float4*)(w_cpe + j * CC + c0);
    a0 += fp82f<0>(d) * wj.x;
    a1 += fp82f<1>(d) * wj.y;
    a2 += fp82f<2>(d) * wj.z;
    a3 += fp82f<3>(d) * wj.w;
  }

  const float4 dv = *(const float4*)(data + (size_t)n * CC + c0);
  const float4 g4 = *(const float4*)(bn_g + c0);
  const float4 b4 = *(const float4*)(bn_b + c0);
  float x0 = dv.x + a0 * g4.x + b4.x;
  float x1 = dv.y + a1 * g4.y + b4.y;
  float x2 = dv.z + a2 * g4.z + b4.z;
  float x3 = dv.w + a3 * g4.w + b4.w;
  *(float4*)(xo + (size_t)n * CC + c0) = make_float4(x0, x1, x2, x3);

  float s  = x0 + x1 + x2 + x3;
  float s2 = x0 * x0 + x1 * x1 + x2 * x2 + x3 * x3;
#pragma unroll
  for (int m = 1; m <= 32; m <<= 1) { s += __shfl_xor(s, m); s2 += __shfl_xor(s2, m); }
  const float mean = s * (1.f / 256.f);
  const float var  = s2 * (1.f / 256.f) - mean * mean;
  const float inv  = rsqrtf(var + 1e-5f);

  const float4 ng = *(const float4*)(n1_g + c0);
  const float4 nb4 = *(const float4*)(n1_b + c0);
  u32x2 o;
  o[0] = (u32)f2b((x0 - mean) * inv * ng.x + nb4.x) |
         ((u32)f2b((x1 - mean) * inv * ng.y + nb4.y) << 16);
  o[1] = (u32)f2b((x2 - mean) * inv * ng.z + nb4.z) |
         ((u32)f2b((x3 - mean) * inv * ng.w + nb4.w) << 16);
  *(u32x2*)(ho + (size_t)n * CC + c0) = o;
}

// ---------------- LN2 (wave per row) ----------------
__global__ __launch_bounds__(256) void k_ln2(const float* __restrict__ x,
                                             const float* __restrict__ g,
                                             const float* __restrict__ b,
                                             u16* __restrict__ h) {
  const int row = blockIdx.x * 4 + (threadIdx.x >> 6);
  const int l = threadIdx.x & 63;
  const float4 xv = ((const float4*)(x + (size_t)row * CC))[l];
  float s  = xv.x + xv.y + xv.z + xv.w;
  float s2 = xv.x * xv.x + xv.y * xv.y + xv.z * xv.z + xv.w * xv.w;
#pragma unroll
  for (int m = 1; m <= 32; m <<= 1) { s += __shfl_xor(s, m); s2 += __shfl_xor(s2, m); }
  const float mean = s * (1.f / 256.f);
  const float var  = s2 * (1.f / 256.f) - mean * mean;
  const float inv  = rsqrtf(var + 1e-5f);
  const int c = l * 4;
  ushort4 o;
  o.x = f2b((xv.x - mean) * inv * g[c + 0] + b[c + 0]);
  o.y = f2b((xv.y - mean) * inv * g[c + 1] + b[c + 1]);
  o.z = f2b((xv.z - mean) * inv * g[c + 2] + b[c + 2]);
  o.w = f2b((xv.w - mean) * inv * g[c + 3] + b[c + 3]);
  ((ushort4*)(h + (size_t)row * CC))[l] = o;
}

// ---------------- MFMA GEMM: C[M][ND] = A[M][KD] * Bt[ND][KD]^T ----------------
// EPI 0: out_bf16 = acc + bias
// EPI 1: out_f32 += acc + bias            (residual accumulate)
// EPI 2: out_bf16 = gelu_exact(acc + bias)
template <int KD, int ND, int EPI>
__global__ __launch_bounds__(256) void k_gemm(const u16* __restrict__ A,
                                              const u16* __restrict__ Bt,
                                              const float* __restrict__ bias,
                                              u16* __restrict__ outb,
                                              float* __restrict__ outf) {
  __shared__ __align__(16) u16 As[128 * 64];
  __shared__ __align__(16) u16 Bs[128 * 64];
  const int tid = threadIdx.x;
  const int lane = tid & 63;
  const int wv = tid >> 6;
  const int wm = (wv >> 1) * 64;
  const int wn = (wv & 1) * 64;
  const int l15 = lane & 15;
  const int lhi = lane >> 4;
  const int m0 = blockIdx.y * 128;
  const int n0 = blockIdx.x * 128;

  f32x4 acc[4][4] = {};

  for (int k0 = 0; k0 < KD; k0 += 64) {
#pragma unroll
    for (int i = 0; i < 4; i++) {
      const int off = i * 4096 + tid * 16;     // byte offset in 16KB tile
      const int row = off >> 7;                // 128B (=64 bf16) per row
      const int ke  = (off & 127) >> 1;        // element offset in K
      gload_lds16(A  + (size_t)(m0 + row) * KD + k0 + ke, (char*)As + off);
      gload_lds16(Bt + (size_t)(n0 + row) * KD + k0 + ke, (char*)Bs + off);
    }
    __syncthreads();
#pragma unroll
    for (int kk = 0; kk < 2; kk++) {
      bf16x8 fa[4], fb[4];
#pragma unroll
      for (int t = 0; t < 4; t++) {
        fa[t] = *(const bf16x8*)&As[(wm + t * 16 + l15) * 64 + kk * 32 + lhi * 8];
        fb[t] = *(const bf16x8*)&Bs[(wn + t * 16 + l15) * 64 + kk * 32 + lhi * 8];
      }
#pragma unroll
      for (int mi = 0; mi < 4; mi++)
#pragma unroll
        for (int ni = 0; ni < 4; ni++)
          acc[mi][ni] = __builtin_amdgcn_mfma_f32_16x16x32_bf16(fa[mi], fb[ni],
                                                                acc[mi][ni], 0, 0, 0);
    }
    __syncthreads();
  }

#pragma unroll
  for (int mi = 0; mi < 4; mi++) {
#pragma unroll
    for (int ni = 0; ni < 4; ni++) {
      const int col = n0 + wn + ni * 16 + l15;
      const float bc = bias[col];
#pragma unroll
      for (int r = 0; r < 4; r++) {
        const int row = m0 + wm + mi * 16 + lhi * 4 + r;
        const size_t o = (size_t)row * ND + col;
        float v = acc[mi][ni][r] + bc;
        if constexpr (EPI == 0) {
          outb[o] = f2b(v);
        } else if constexpr (EPI == 1) {
          outf[o] += v;
        } else {
          v = 0.5f * v * (1.0f + erff(v * 0.70710678118654752f));
          outb[o] = f2b(v);
        }
      }
    }
  }
}

// ---------------- windowed attention with RPE (MFMA version) ----------------
// 1 block = 1 window, 512 threads = 8 waves, wave w = head w.
// LDS: sQ/sK/sV per head [32 rows][40 u16] (80B padded rows, head stride 1288 u16),
// sT = rpe table transposed [8][153] f32. P reuses sQ[h]; O_lds reuses sK.
__global__ __launch_bounds__(512, 4) void k_attn(const u16* __restrict__ qkv,
                                                 const int* __restrict__ rel_pos,
                                                 const float* __restrict__ pmask,
                                                 const float* __restrict__ rpet,
                                                 u16* __restrict__ out) {
  constexpr int HS = 1288;                      // u16 per head region (2576 B)
  __shared__ __align__(16) u16 smem[24 * HS + 2448];
  u16* sQ = smem;
  u16* sK = smem + 8 * HS;                      // overlaid by O_lds [32][264] later
  u16* sV = smem + 16 * HS;                     // V^T per head: [d][p], rows 40 u16
  float* sT = (float*)(smem + 24 * HS);         // [8][153]

  const int tid = threadIdx.x;
  const int nw  = blockIdx.x;
  const int w32 = nw * 32;

  // ---- stage rpe table transposed: sT[h*153 + ix] = rpet[ix*8 + h] ----
  for (int i = tid; i < 1224; i += 512) {
    int h = i / 153, ix = i - h * 153;
    sT[i] = rpet[ix * 8 + h];
  }
  // ---- stage Q, K: 2048 16B chunks ----
#pragma unroll
  for (int j = 0; j < 4; j++) {
    int id  = j * 512 + tid;
    int mat = id >> 10;                         // 0 = Q, 1 = K (wave-uniform)
    int id1 = id & 1023;
    int h = id1 >> 7, q = (id1 >> 2) & 31, s = id1 & 3;
    u32x4 v = *(const u32x4*)(qkv + (size_t)(w32 + q) * 768 + mat * 256 + h * 32 + s * 8);
    u16* dst = (mat ? sK : sQ) + h * HS + q * 40 + s * 8;
    *(u32x4*)dst = v;
  }
  // ---- stage V transposed: VT[h][d&31][p] ----
#pragma unroll
  for (int j = 0; j < 2; j++) {
    int id = j * 512 + tid;
    int p = id >> 5, dc = id & 31;
    u32x4 v = *(const u32x4*)(qkv + (size_t)(w32 + p) * 768 + 512 + dc * 8);
    const u16* pv = (const u16*)&v;
#pragma unroll
    for (int jj = 0; jj < 8; jj++) {
      int d = dc * 8 + jj;
      sV[(d >> 5) * HS + (d & 31) * 40 + p] = pv[jj];
    }
  }
  __syncthreads();

  const int h = tid >> 6;
  const int lane = tid & 63;
  const int g = lane >> 4, c = lane & 15;
  const f32x4 zero = {0.f, 0.f, 0.f, 0.f};

  // ---- QK^T via MFMA: S[q][k], tiles (qt,kt) ----
  bf16x8 fq[2], fk[2];
#pragma unroll
  for (int t = 0; t < 2; t++) {
    fq[t] = *(const bf16x8*)&sQ[h * HS + (t * 16 + c) * 40 + g * 8];
    fk[t] = *(const bf16x8*)&sK[h * HS + (t * 16 + c) * 40 + g * 8];
  }
  f32x4 S[2][2];
#pragma unroll
  for (int qt = 0; qt < 2; qt++)
#pragma unroll
    for (int kt = 0; kt < 2; kt++)
      S[qt][kt] = __builtin_amdgcn_mfma_f32_16x16x32_bf16(fq[qt], fk[kt], zero, 0, 0, 0);

  // ---- bias (rpe + mask) + scale + softmax per q-row, write P to sQ[h] ----
  const float sc = 0.17677669529663687f;  // 32^-0.5
#pragma unroll
  for (int qt = 0; qt < 2; qt++) {
#pragma unroll
    for (int r = 0; r < 4; r++) {
      const int q = qt * 16 + g * 4 + r;
      const int* rp = rel_pos + ((size_t)(w32 + q) * 32) * 3;
      const float* pm = pmask + (size_t)(w32 + q) * 32;
      float v[2];
#pragma unroll
      for (int kt = 0; kt < 2; kt++) {
        const int k = kt * 16 + c;
        int r0 = rp[k * 3], r1 = rp[k * 3 + 1], r2 = rp[k * 3 + 2];
        r0 = min(max(r0, -25), 25);
        r1 = min(max(r1, -25), 25);
        r2 = min(max(r2, -25), 25);
        const float b = sT[h * 153 + 25 + r0] + sT[h * 153 + 76 + r1] +
                        sT[h * 153 + 127 + r2] + pm[k];
        v[kt] = S[qt][kt][r] * sc + b;
      }
      float m = fmaxf(v[0], v[1]);
#pragma unroll
      for (int d = 1; d <= 8; d <<= 1) m = fmaxf(m, __shfl_xor(m, d));
      const float e0 = __expf(v[0] - m);
      const float e1 = __expf(v[1] - m);
      float ssum = e0 + e1;
#pragma unroll
      for (int d = 1; d <= 8; d <<= 1) ssum += __shfl_xor(ssum, d);
      const float inv = 1.0f / ssum;
      sQ[h * HS + q * 40 + c]      = f2b(e0 * inv);
      sQ[h * HS + q * 40 + 16 + c] = f2b(e1 * inv);
    }
  }
  __builtin_amdgcn_sched_barrier(0);  // P writes stay before P-fragment reads

  // ---- PV via MFMA: O^T[d][q] = sum_k VT[d][k] * P[q][k] ----
  bf16x8 fp[2], fv[2];
#pragma unroll
  for (int t = 0; t < 2; t++) {
    fp[t] = *(const bf16x8*)&sQ[h * HS + (t * 16 + c) * 40 + g * 8];
    fv[t] = *(const bf16x8*)&sV[h * HS + (t * 16 + c) * 40 + g * 8];
  }
  f32x4 OT[2][2];
#pragma unroll
  for (int dt = 0; dt < 2; dt++)
#pragma unroll
    for (int qt = 0; qt < 2; qt++)
      OT[dt][qt] = __builtin_amdgcn_mfma_f32_16x16x32_bf16(fv[dt], fp[qt], zero, 0, 0, 0);

  __syncthreads();                     // all waves done reading K: reuse sK as O_lds
  u16* OL = sK;                        // [32 rows][264 u16] (528B padded rows)
#pragma unroll
  for (int dt = 0; dt < 2; dt++)
#pragma unroll
    for (int qt = 0; qt < 2; qt++)
#pragma unroll
      for (int r = 0; r < 4; r++) {
        const int d = dt * 16 + g * 4 + r, q = qt * 16 + c;
        OL[q * 264 + h * 32 + d] = f2b(OT[dt][qt][r]);
      }
  __syncthreads();

  // ---- cooperative coalesced store: 32 rows x 512B ----
  {
    const int q = tid >> 4, ch = tid & 15;
    u32x4 w0 = *(const u32x4*)&OL[q * 264 + ch * 16];
    u32x4 w1 = *(const u32x4*)&OL[q * 264 + ch * 16 + 8];
    u16* ob = out + (size_t)(w32 + q) * 256 + ch * 16;
    *(u32x4*)ob = w0;
    *((u32x4*)ob + 1) = w1;
  }
}

extern "C" void kernel_launch(void* const* d_in, const int* in_sizes, int n_in,
                              void* d_out, int out_size, void* d_ws, size_t ws_size,
                              hipStream_t stream) {
  const float* data   = (const float*)d_in[0];
  const int*   nbr    = (const int*)d_in[1];
  const int*   relpos = (const int*)d_in[2];
  const float* pmask  = (const float*)d_in[3];
  const float* w_cpe  = (const float*)d_in[4];
  const float* bn_g   = (const float*)d_in[5];
  const float* bn_b   = (const float*)d_in[6];
  const float* n1_g   = (const float*)d_in[7];
  const float* n1_b   = (const float*)d_in[8];
  const float* w_qkv  = (const float*)d_in[9];
  const float* b_qkv  = (const float*)d_in[10];
  const float* w_proj = (const float*)d_in[11];
  const float* b_proj = (const float*)d_in[12];
  const float* rpet   = (const float*)d_in[13];
  const float* n2_g   = (const float*)d_in[14];
  const float* n2_b   = (const float*)d_in[15];
  const float* w_fc1  = (const float*)d_in[16];
  const float* b_fc1  = (const float*)d_in[17];
  const float* w_fc2  = (const float*)d_in[18];
  const float* b_fc2  = (const float*)d_in[19];
  float* xout = (float*)d_out;  // residual stream x lives in d_out (f32)

  char* pw = (char*)d_ws;
  u16* buf1 = (u16*)pw; pw += (size_t)NPT * 1024 * 2;  // fp8 data copy / qkv / ffn hidden
  u16* buf2 = (u16*)pw; pw += (size_t)NPT * 256 * 2;   // h / attn_out / h2
  u16* wqkvT = (u16*)pw; pw += 768 * 256 * 2;
  u16* wprojT = (u16*)pw; pw += 256 * 256 * 2;
  u16* wfc1T = (u16*)pw; pw += 1024 * 256 * 2;
  u16* wfc2T = (u16*)pw; pw += 256 * 1024 * 2;
  u8* data8 = (u8*)buf1;  // 32 MB fp8 copy, consumed before buf1 is reused by QKV

  // prep: fp8 copy of data (for CPE gathers), transposed bf16 weights
  k_f2b8<<<2048, 256, 0, stream>>>(data, data8, NPT * 256 / 4);
  k_transpose_f2b<<<(256 * 768 + 255) / 256, 256, 0, stream>>>(w_qkv, wqkvT, 256, 768);
  k_transpose_f2b<<<(256 * 256 + 255) / 256, 256, 0, stream>>>(w_proj, wprojT, 256, 256);
  k_transpose_f2b<<<(256 * 1024 + 255) / 256, 256, 0, stream>>>(w_fc1, wfc1T, 256, 1024);
  k_transpose_f2b<<<(1024 * 256 + 255) / 256, 256, 0, stream>>>(w_fc2, wfc2T, 1024, 256);

  // CPE + residual + LN1:  x -> d_out(f32), h -> buf2(bf16)
  k_cpe_ln1<<<NPT / 4, 256, 0, stream>>>(data, nbr, data8, w_cpe, bn_g, bn_b, n1_g, n1_b,
                                         xout, buf2);
  // QKV = h @ w_qkv + b  -> buf1 (bf16, N x 768)
  k_gemm<256, 768, 0><<<dim3(6, 1024), 256, 0, stream>>>(buf2, wqkvT, b_qkv, buf1, nullptr);
  // attention -> buf2 (bf16, N x 256)
  k_attn<<<NWIN, 512, 0, stream>>>(buf1, relpos, pmask, rpet, buf2);
  // x += attn_out @ w_proj + b
  k_gemm<256, 256, 1><<<dim3(2, 1024), 256, 0, stream>>>(buf2, wprojT, b_proj, nullptr, xout);
  // h2 = LN2(x) -> buf2
  k_ln2<<<NPT / 4, 256, 0, stream>>>(xout, n2_g, n2_b, buf2);
  // hidden = gelu(h2 @ w_fc1 + b) -> buf1 (bf16, N x 1024)
  k_gemm<256, 1024, 2><<<dim3(8, 1024), 256, 0, stream>>>(buf2, wfc1T, b_fc1, buf1, nullptr);
  // x += hidden @ w_fc2 + b   (final output in d_out)
  k_gemm<1024, 256, 1><<<dim3(2, 1024), 256, 0, stream>>>(buf1, wfc2T, b_fc2, nullptr, xout);
}

// Round 9
// 916.329 us; speedup vs baseline: 1.4434x; 1.0442x over previous
//
#include <hip/hip_runtime.h>
#include <stdint.h>

// OctFormer block, MI355X gfx950.
// Pipeline: [fp8 data copy] [prep weights] -> CPE+LN1 -> QKV GEMM -> attn ->
//           proj GEMM(+resid+LN2 fused) -> FC1 GEMM(+gelu) -> FC2 GEMM(+resid -> d_out)
// Residual stream x lives in d_out (f32). GEMMs: bf16 MFMA 16x16x32, 128-tiles,
// global_load_lds staging, XCD-aware block swizzle.
// CPE: 1 wave/point, fp8 rows, two-phase batched gathers (27 loads in flight).

static constexpr int NPT   = 131072;  // points
static constexpr int CC    = 256;     // channels
static constexpr int NWIN  = 4096;    // windows
static constexpr int NHEAD = 8;

using u16 = unsigned short;
using u32 = unsigned int;
using u8  = unsigned char;

typedef __bf16 bf16x8 __attribute__((ext_vector_type(8)));
typedef float  f32x4  __attribute__((ext_vector_type(4)));
typedef u32    u32x4  __attribute__((ext_vector_type(4)));
typedef u32    u32x2  __attribute__((ext_vector_type(2)));

__device__ __forceinline__ float b2f(u16 u) {
  union { float f; u32 i; } v; v.i = ((u32)u) << 16; return v.f;
}
__device__ __forceinline__ u16 f2b(float f) {  // RNE f32 -> bf16
  u32 x = __float_as_uint(f);
  return (u16)((x + 0x7fffu + ((x >> 16) & 1u)) >> 16);
}

// ---- OCP e4m3fn encode (RNE). Inputs here are |x| <= ~6, no saturation path.
__device__ __forceinline__ u8 f2fp8(float f) {
  const u32 s = (__float_as_uint(f) >> 24) & 0x80u;
  float a = fabsf(f);
  if (a >= 0.015625f) {                       // normal range
    u32 b = __float_as_uint(a);
    u32 rb = b + 0x7FFFFu + ((b >> 20) & 1u); // RNE on 3 mantissa bits
    u32 E = (rb >> 23) - 120u;                // exp bias 7
    return (u8)(s | (E << 3) | ((rb >> 20) & 7u));
  }
  int k = (int)rintf(a * 512.0f);             // denormal: multiples of 2^-9
  return (u8)(s | (u32)k);
}

// ---- OCP e4m3fn decode: byte J (compile-time) of dword d.
template <int J>
__device__ __forceinline__ float fp82f(u32 d) {
#if defined(__has_builtin)
#if __has_builtin(__builtin_amdgcn_cvt_f32_fp8)
  return __builtin_amdgcn_cvt_f32_fp8(d, J);
#else
  const u32 u = (d >> (8 * J)) & 0xFFu;
  const u32 e = (u >> 3) & 15u, m = u & 7u;
  float v = e ? __uint_as_float(((e + 120u) << 23) | (m << 20))
              : (float)m * 0.001953125f;
  return (u & 0x80u) ? -v : v;
#endif
#else
  const u32 u = (d >> (8 * J)) & 0xFFu;
  const u32 e = (u >> 3) & 15u, m = u & 7u;
  float v = e ? __uint_as_float(((e + 120u) << 23) | (m << 20))
              : (float)m * 0.001953125f;
  return (u & 0x80u) ? -v : v;
#endif
}

__device__ __forceinline__ void gload_lds16(const void* g, void* l) {
  using gptr_t = const __attribute__((address_space(1))) uint32_t*;
  using lptr_t = __attribute__((address_space(3))) uint32_t*;
  __builtin_amdgcn_global_load_lds((gptr_t)(uintptr_t)g,
                                   (lptr_t)(uint32_t)(uintptr_t)l, 16, 0, 0);
}

// ---------------- f32 -> fp8 e4m3 bulk convert ----------------
__global__ __launch_bounds__(256) void k_f2b8(const float* __restrict__ in,
                                              u8* __restrict__ out, int n4) {
  for (int i = blockIdx.x * 256 + threadIdx.x; i < n4; i += gridDim.x * 256) {
    float4 v = ((const float4*)in)[i];
    u32 o = (u32)f2fp8(v.x) | ((u32)f2fp8(v.y) << 8) |
            ((u32)f2fp8(v.z) << 16) | ((u32)f2fp8(v.w) << 24);
    ((u32*)out)[i] = o;
  }
}

// ---------------- all 4 weight transposes (+bf16 convert) in one launch --------
__global__ __launch_bounds__(256) void k_prep_w(
    const float* __restrict__ wqkv, const float* __restrict__ wproj,
    const float* __restrict__ wfc1, const float* __restrict__ wfc2,
    u16* __restrict__ oqkv, u16* __restrict__ oproj,
    u16* __restrict__ ofc1, u16* __restrict__ ofc2) {
  int i = blockIdx.x * 256 + threadIdx.x;
  if (i < 196608) {                       // w_qkv 256x768 -> [768][256]
    int c = i >> 8, r = i & 255; oqkv[i] = f2b(wqkv[r * 768 + c]);
  } else if (i < 262144) {                // w_proj 256x256
    i -= 196608; int c = i >> 8, r = i & 255; oproj[i] = f2b(wproj[r * 256 + c]);
  } else if (i < 524288) {                // w_fc1 256x1024 -> [1024][256]
    i -= 262144; int c = i >> 8, r = i & 255; ofc1[i] = f2b(wfc1[r * 1024 + c]);
  } else {                                // w_fc2 1024x256 -> [256][1024]
    i -= 524288; int c = i >> 10, r = i & 1023; ofc2[i] = f2b(wfc2[r * 256 + c]);
  }
}

// ---------------- CPE gather + residual + LN1 (wave/point, two-phase) ----------
// Phase 1: issue all 27 row-loads (d[27] statically indexed -> registers, full
// MLP). Phase 2: fp8-decode + FMA. Lane owns channels [4*lane, 4*lane+4).
__global__ __launch_bounds__(256) void k_cpe_ln1(
    const float* __restrict__ data, const int* __restrict__ nbr,
    const u8* __restrict__ datab, const float* __restrict__ w_cpe,
    const float* __restrict__ bn_g, const float* __restrict__ bn_b,
    const float* __restrict__ n1_g, const float* __restrict__ n1_b,
    float* __restrict__ xo, u16* __restrict__ ho) {
  const int wv   = threadIdx.x >> 6;
  const int lane = threadIdx.x & 63;
  const int n    = blockIdx.x * 4 + wv;
  const int c0   = lane * 4;

  int myidx = 0;
  if (lane < 27) myidx = nbr[n * 27 + lane];

  u32 d[27];
#pragma unroll
  for (int j = 0; j < 27; j++) {
    const int idx = __builtin_amdgcn_readlane(myidx, j);
    d[j] = *(const u32*)(datab + (size_t)idx * CC + c0);
  }

  float a0 = 0.f, a1 = 0.f, a2 = 0.f, a3 = 0.f;
#pragma unroll
  for (int j = 0; j < 27; j++) {
    const float4 wj = *(const float4*)(w_cpe + j * CC + c0);
    a0 += fp82f<0>(d[j]) * wj.x;
    a1 += fp82f<1>(d[j]) * wj.y;
    a2 += fp82f<2>(d[j]) * wj.z;
    a3 += fp82f<3>(d[j]) * wj.w;
  }

  const float4 dv = *(const float4*)(data + (size_t)n * CC + c0);
  const float4 g4 = *(const float4*)(bn_g + c0);
  const float4 b4 = *(const float4*)(bn_b + c0);
  float x0 = dv.x + a0 * g4.x + b4.x;
  float x1 = dv.y + a1 * g4.y + b4.y;
  float x2 = dv.z + a2 * g4.z + b4.z;
  float x3 = dv.w + a3 * g4.w + b4.w;
  *(float4*)(xo + (size_t)n * CC + c0) = make_float4(x0, x1, x2, x3);

  float s  = x0 + x1 + x2 + x3;
  float s2 = x0 * x0 + x1 * x1 + x2 * x2 + x3 * x3;
#pragma unroll
  for (int m = 1; m <= 32; m <<= 1) { s += __shfl_xor(s, m); s2 += __shfl_xor(s2, m); }
  const float mean = s * (1.f / 256.f);
  const float var  = s2 * (1.f / 256.f) - mean * mean;
  const float inv  = rsqrtf(var + 1e-5f);

  const float4 ng = *(const float4*)(n1_g + c0);
  const float4 nb4 = *(const float4*)(n1_b + c0);
  u32x2 o;
  o[0] = (u32)f2b((x0 - mean) * inv * ng.x + nb4.x) |
         ((u32)f2b((x1 - mean) * inv * ng.y + nb4.y) << 16);
  o[1] = (u32)f2b((x2 - mean) * inv * ng.z + nb4.z) |
         ((u32)f2b((x3 - mean) * inv * ng.w + nb4.w) << 16);
  *(u32x2*)(ho + (size_t)n * CC + c0) = o;
}

// ---------------- MFMA GEMM: C[M][ND] = A[M][KD] * Bt[ND][KD]^T ----------------
// XCD-aware swizzle (nwg % 8 == 0 for all instantiations).
// EPI 0: out_bf16 = acc + bias
// EPI 1: out_f32 += acc + bias            (residual accumulate)
// EPI 2: out_bf16 = gelu_exact(acc + bias)
template <int KD, int ND, int EPI>
__global__ __launch_bounds__(256) void k_gemm(const u16* __restrict__ A,
                                              const u16* __restrict__ Bt,
                                              const float* __restrict__ bias,
                                              u16* __restrict__ outb,
                                              float* __restrict__ outf) {
  __shared__ __align__(16) u16 As[128 * 64];
  __shared__ __align__(16) u16 Bs[128 * 64];
  const int tid = threadIdx.x;
  const int lane = tid & 63;
  const int wv = tid >> 6;
  const int wm = (wv >> 1) * 64;
  const int wn = (wv & 1) * 64;
  const int l15 = lane & 15;
  const int lhi = lane >> 4;

  // XCD swizzle: consecutive HW blocks (round-robin over 8 XCDs) -> same XCD
  // walks contiguous tiles, so same-m A-panels stay in one XCD's L2.
  const int gx = gridDim.x;
  const int bid = blockIdx.y * gx + blockIdx.x;
  const int cpx = (gx * gridDim.y) >> 3;
  const int swz = (bid & 7) * cpx + (bid >> 3);
  const int m0 = (swz / gx) * 128;
  const int n0 = (swz % gx) * 128;

  f32x4 acc[4][4] = {};

  for (int k0 = 0; k0 < KD; k0 += 64) {
#pragma unroll
    for (int i = 0; i < 4; i++) {
      const int off = i * 4096 + tid * 16;     // byte offset in 16KB tile
      const int row = off >> 7;                // 128B (=64 bf16) per row
      const int ke  = (off & 127) >> 1;        // element offset in K
      gload_lds16(A  + (size_t)(m0 + row) * KD + k0 + ke, (char*)As + off);
      gload_lds16(Bt + (size_t)(n0 + row) * KD + k0 + ke, (char*)Bs + off);
    }
    __syncthreads();
#pragma unroll
    for (int kk = 0; kk < 2; kk++) {
      bf16x8 fa[4], fb[4];
#pragma unroll
      for (int t = 0; t < 4; t++) {
        fa[t] = *(const bf16x8*)&As[(wm + t * 16 + l15) * 64 + kk * 32 + lhi * 8];
        fb[t] = *(const bf16x8*)&Bs[(wn + t * 16 + l15) * 64 + kk * 32 + lhi * 8];
      }
#pragma unroll
      for (int mi = 0; mi < 4; mi++)
#pragma unroll
        for (int ni = 0; ni < 4; ni++)
          acc[mi][ni] = __builtin_amdgcn_mfma_f32_16x16x32_bf16(fa[mi], fb[ni],
                                                                acc[mi][ni], 0, 0, 0);
    }
    __syncthreads();
  }

#pragma unroll
  for (int mi = 0; mi < 4; mi++) {
#pragma unroll
    for (int ni = 0; ni < 4; ni++) {
      const int col = n0 + wn + ni * 16 + l15;
      const float bc = bias[col];
#pragma unroll
      for (int r = 0; r < 4; r++) {
        const int row = m0 + wm + mi * 16 + lhi * 4 + r;
        const size_t o = (size_t)row * ND + col;
        float v = acc[mi][ni][r] + bc;
        if constexpr (EPI == 0) {
          outb[o] = f2b(v);
        } else if constexpr (EPI == 1) {
          outf[o] += v;
        } else {
          v = 0.5f * v * (1.0f + erff(v * 0.70710678118654752f));
          outb[o] = f2b(v);
        }
      }
    }
  }
}

// ---------------- proj GEMM + residual + LN2 fused ----------------
// Tile 128 rows x 256 cols (full width) so each wave owns complete rows.
// Wave wv covers rows [wv*32, wv*32+32); per-row LN via 16-lane shfl reduce.
// x += attn@wprojT + b; h2 = LN(x)*g + b -> bf16.
__global__ __launch_bounds__(256) void k_proj_ln2(
    const u16* __restrict__ A, const u16* __restrict__ Bt,
    const float* __restrict__ bias, float* __restrict__ xo,
    const float* __restrict__ n2g, const float* __restrict__ n2b,
    u16* __restrict__ h2) {
  __shared__ __align__(16) u16 As[128 * 64];
  __shared__ __align__(16) u16 Bs[256 * 64];
  const int tid = threadIdx.x;
  const int lane = tid & 63;
  const int wv = tid >> 6;
  const int l15 = lane & 15;
  const int g = lane >> 4;
  const int m0 = blockIdx.x * 128;
  const int wm = wv * 32;

  f32x4 acc[2][16] = {};

  for (int k0 = 0; k0 < 256; k0 += 64) {
#pragma unroll
    for (int i = 0; i < 4; i++) {
      const int off = i * 4096 + tid * 16;
      const int row = off >> 7, ke = (off & 127) >> 1;
      gload_lds16(A + (size_t)(m0 + row) * 256 + k0 + ke, (char*)As + off);
    }
#pragma unroll
    for (int i = 0; i < 8; i++) {
      const int off = i * 4096 + tid * 16;
      const int row = off >> 7, ke = (off & 127) >> 1;
      gload_lds16(Bt + (size_t)row * 256 + k0 + ke, (char*)Bs + off);
    }
    __syncthreads();
#pragma unroll
    for (int kk = 0; kk < 2; kk++) {
      bf16x8 fa[2];
#pragma unroll
      for (int t = 0; t < 2; t++)
        fa[t] = *(const bf16x8*)&As[(wm + t * 16 + l15) * 64 + kk * 32 + g * 8];
#pragma unroll
      for (int ni = 0; ni < 16; ni++) {
        bf16x8 fb = *(const bf16x8*)&Bs[(ni * 16 + l15) * 64 + kk * 32 + g * 8];
#pragma unroll
        for (int mi = 0; mi < 2; mi++)
          acc[mi][ni] = __builtin_amdgcn_mfma_f32_16x16x32_bf16(fa[mi], fb,
                                                                acc[mi][ni], 0, 0, 0);
      }
    }
    __syncthreads();
  }

  // epilogue: bias + residual + per-row LN (row held by one 16-lane group)
#pragma unroll
  for (int mi = 0; mi < 2; mi++) {
#pragma unroll
    for (int r = 0; r < 4; r++) {
      const int row = m0 + wm + mi * 16 + g * 4 + r;
      float v[16];
      float s = 0.f, s2 = 0.f;
#pragma unroll
      for (int ni = 0; ni < 16; ni++) {
        const int col = ni * 16 + l15;
        float t = acc[mi][ni][r] + bias[col] + xo[(size_t)row * 256 + col];
        v[ni] = t; s += t; s2 += t * t;
      }
#pragma unroll
      for (int m = 1; m <= 8; m <<= 1) { s += __shfl_xor(s, m); s2 += __shfl_xor(s2, m); }
      const float mean = s * (1.f / 256.f);
      const float var  = s2 * (1.f / 256.f) - mean * mean;
      const float inv  = rsqrtf(var + 1e-5f);
#pragma unroll
      for (int ni = 0; ni < 16; ni++) {
        const int col = ni * 16 + l15;
        xo[(size_t)row * 256 + col] = v[ni];
        h2[(size_t)row * 256 + col] = f2b((v[ni] - mean) * inv * n2g[col] + n2b[col]);
      }
    }
  }
}

// ---------------- windowed attention with RPE (MFMA version) ----------------
// 1 block = 1 window, 512 threads = 8 waves, wave w = head w.
// LDS: sQ/sK/sV per head [32 rows][40 u16] (80B padded rows, head stride 1288 u16),
// sT = rpe table transposed [8][153] f32. P reuses sQ[h]; O_lds reuses sK.
__global__ __launch_bounds__(512, 4) void k_attn(const u16* __restrict__ qkv,
                                                 const int* __restrict__ rel_pos,
                                                 const float* __restrict__ pmask,
                                                 const float* __restrict__ rpet,
                                                 u16* __restrict__ out) {
  constexpr int HS = 1288;                      // u16 per head region (2576 B)
  __shared__ __align__(16) u16 smem[24 * HS + 2448];
  u16* sQ = smem;
  u16* sK = smem + 8 * HS;                      // overlaid by O_lds [32][264] later
  u16* sV = smem + 16 * HS;                     // V^T per head: [d][p], rows 40 u16
  float* sT = (float*)(smem + 24 * HS);         // [8][153]

  const int tid = threadIdx.x;
  const int nw  = blockIdx.x;
  const int w32 = nw * 32;

  // ---- stage rpe table transposed: sT[h*153 + ix] = rpet[ix*8 + h] ----
  for (int i = tid; i < 1224; i += 512) {
    int h = i / 153, ix = i - h * 153;
    sT[i] = rpet[ix * 8 + h];
  }
  // ---- stage Q, K: 2048 16B chunks ----
#pragma unroll
  for (int j = 0; j < 4; j++) {
    int id  = j * 512 + tid;
    int mat = id >> 10;                         // 0 = Q, 1 = K (wave-uniform)
    int id1 = id & 1023;
    int h = id1 >> 7, q = (id1 >> 2) & 31, s = id1 & 3;
    u32x4 v = *(const u32x4*)(qkv + (size_t)(w32 + q) * 768 + mat * 256 + h * 32 + s * 8);
    u16* dst = (mat ? sK : sQ) + h * HS + q * 40 + s * 8;
    *(u32x4*)dst = v;
  }
  // ---- stage V transposed: VT[h][d&31][p] ----
#pragma unroll
  for (int j = 0; j < 2; j++) {
    int id = j * 512 + tid;
    int p = id >> 5, dc = id & 31;
    u32x4 v = *(const u32x4*)(qkv + (size_t)(w32 + p) * 768 + 512 + dc * 8);
    const u16* pv = (const u16*)&v;
#pragma unroll
    for (int jj = 0; jj < 8; jj++) {
      int d = dc * 8 + jj;
      sV[(d >> 5) * HS + (d & 31) * 40 + p] = pv[jj];
    }
  }
  __syncthreads();

  const int h = tid >> 6;
  const int lane = tid & 63;
  const int g = lane >> 4, c = lane & 15;
  const f32x4 zero = {0.f, 0.f, 0.f, 0.f};

  // ---- QK^T via MFMA: S[q][k], tiles (qt,kt) ----
  bf16x8 fq[2], fk[2];
#pragma unroll
  for (int t = 0; t < 2; t++) {
    fq[t] = *(const bf16x8*)&sQ[h * HS + (t * 16 + c) * 40 + g * 8];
    fk[t] = *(const bf16x8*)&sK[h * HS + (t * 16 + c) * 40 + g * 8];
  }
  f32x4 S[2][2];
#pragma unroll
  for (int qt = 0; qt < 2; qt++)
#pragma unroll
    for (int kt = 0; kt < 2; kt++)
      S[qt][kt] = __builtin_amdgcn_mfma_f32_16x16x32_bf16(fq[qt], fk[kt], zero, 0, 0, 0);

  // ---- bias (rpe + mask) + scale + softmax per q-row, write P to sQ[h] ----
  const float sc = 0.17677669529663687f;  // 32^-0.5
#pragma unroll
  for (int qt = 0; qt < 2; qt++) {
#pragma unroll
    for (int r = 0; r < 4; r++) {
      const int q = qt * 16 + g * 4 + r;
      const int* rp = rel_pos + ((size_t)(w32 + q) * 32) * 3;
      const float* pm = pmask + (size_t)(w32 + q) * 32;
      float v[2];
#pragma unroll
      for (int kt = 0; kt < 2; kt++) {
        const int k = kt * 16 + c;
        int r0 = rp[k * 3], r1 = rp[k * 3 + 1], r2 = rp[k * 3 + 2];
        r0 = min(max(r0, -25), 25);
        r1 = min(max(r1, -25), 25);
        r2 = min(max(r2, -25), 25);
        const float b = sT[h * 153 + 25 + r0] + sT[h * 153 + 76 + r1] +
                        sT[h * 153 + 127 + r2] + pm[k];
        v[kt] = S[qt][kt][r] * sc + b;
      }
      float m = fmaxf(v[0], v[1]);
#pragma unroll
      for (int d = 1; d <= 8; d <<= 1) m = fmaxf(m, __shfl_xor(m, d));
      const float e0 = __expf(v[0] - m);
      const float e1 = __expf(v[1] - m);
      float ssum = e0 + e1;
#pragma unroll
      for (int d = 1; d <= 8; d <<= 1) ssum += __shfl_xor(ssum, d);
      const float inv = 1.0f / ssum;
      sQ[h * HS + q * 40 + c]      = f2b(e0 * inv);
      sQ[h * HS + q * 40 + 16 + c] = f2b(e1 * inv);
    }
  }
  __builtin_amdgcn_sched_barrier(0);  // P writes stay before P-fragment reads

  // ---- PV via MFMA: O^T[d][q] = sum_k VT[d][k] * P[q][k] ----
  bf16x8 fp[2], fv[2];
#pragma unroll
  for (int t = 0; t < 2; t++) {
    fp[t] = *(const bf16x8*)&sQ[h * HS + (t * 16 + c) * 40 + g * 8];
    fv[t] = *(const bf16x8*)&sV[h * HS + (t * 16 + c) * 40 + g * 8];
  }
  f32x4 OT[2][2];
#pragma unroll
  for (int dt = 0; dt < 2; dt++)
#pragma unroll
    for (int qt = 0; qt < 2; qt++)
      OT[dt][qt] = __builtin_amdgcn_mfma_f32_16x16x32_bf16(fv[dt], fp[qt], zero, 0, 0, 0);

  __syncthreads();                     // all waves done reading K: reuse sK as O_lds
  u16* OL = sK;                        // [32 rows][264 u16] (528B padded rows)
#pragma unroll
  for (int dt = 0; dt < 2; dt++)
#pragma unroll
    for (int qt = 0; qt < 2; qt++)
#pragma unroll
      for (int r = 0; r < 4; r++) {
        const int d = dt * 16 + g * 4 + r, q = qt * 16 + c;
        OL[q * 264 + h * 32 + d] = f2b(OT[dt][qt][r]);
      }
  __syncthreads();

  // ---- cooperative coalesced store: 32 rows x 512B ----
  {
    const int q = tid >> 4, ch = tid & 15;
    u32x4 w0 = *(const u32x4*)&OL[q * 264 + ch * 16];
    u32x4 w1 = *(const u32x4*)&OL[q * 264 + ch * 16 + 8];
    u16* ob = out + (size_t)(w32 + q) * 256 + ch * 16;
    *(u32x4*)ob = w0;
    *((u32x4*)ob + 1) = w1;
  }
}

extern "C" void kernel_launch(void* const* d_in, const int* in_sizes, int n_in,
                              void* d_out, int out_size, void* d_ws, size_t ws_size,
                              hipStream_t stream) {
  const float* data   = (const float*)d_in[0];
  const int*   nbr    = (const int*)d_in[1];
  const int*   relpos = (const int*)d_in[2];
  const float* pmask  = (const float*)d_in[3];
  const float* w_cpe  = (const float*)d_in[4];
  const float* bn_g   = (const float*)d_in[5];
  const float* bn_b   = (const float*)d_in[6];
  const float* n1_g   = (const float*)d_in[7];
  const float* n1_b   = (const float*)d_in[8];
  const float* w_qkv  = (const float*)d_in[9];
  const float* b_qkv  = (const float*)d_in[10];
  const float* w_proj = (const float*)d_in[11];
  const float* b_proj = (const float*)d_in[12];
  const float* rpet   = (const float*)d_in[13];
  const float* n2_g   = (const float*)d_in[14];
  const float* n2_b   = (const float*)d_in[15];
  const float* w_fc1  = (const float*)d_in[16];
  const float* b_fc1  = (const float*)d_in[17];
  const float* w_fc2  = (const float*)d_in[18];
  const float* b_fc2  = (const float*)d_in[19];
  float* xout = (float*)d_out;  // residual stream x lives in d_out (f32)

  char* pw = (char*)d_ws;
  u16* buf1 = (u16*)pw; pw += (size_t)NPT * 1024 * 2;  // fp8 data copy / qkv / ffn hidden
  u16* buf2 = (u16*)pw; pw += (size_t)NPT * 256 * 2;   // h / attn_out / h2
  u16* wqkvT = (u16*)pw; pw += 768 * 256 * 2;
  u16* wprojT = (u16*)pw; pw += 256 * 256 * 2;
  u16* wfc1T = (u16*)pw; pw += 1024 * 256 * 2;
  u16* wfc2T = (u16*)pw; pw += 256 * 1024 * 2;
  u8* data8 = (u8*)buf1;  // 32 MB fp8 copy, consumed before buf1 is reused by QKV

  // prep: fp8 copy of data (for CPE gathers), transposed bf16 weights
  k_f2b8<<<2048, 256, 0, stream>>>(data, data8, NPT * 256 / 4);
  k_prep_w<<<3072, 256, 0, stream>>>(w_qkv, w_proj, w_fc1, w_fc2,
                                     wqkvT, wprojT, wfc1T, wfc2T);

  // CPE + residual + LN1:  x -> d_out(f32), h -> buf2(bf16)
  k_cpe_ln1<<<NPT / 4, 256, 0, stream>>>(data, nbr, data8, w_cpe, bn_g, bn_b, n1_g, n1_b,
                                         xout, buf2);
  // QKV = h @ w_qkv + b  -> buf1 (bf16, N x 768)
  k_gemm<256, 768, 0><<<dim3(6, 1024), 256, 0, stream>>>(buf2, wqkvT, b_qkv, buf1, nullptr);
  // attention -> buf2 (bf16, N x 256)
  k_attn<<<NWIN, 512, 0, stream>>>(buf1, relpos, pmask, rpet, buf2);
  // x += attn_out @ w_proj + b; h2 = LN2(x) -> buf2
  k_proj_ln2<<<1024, 256, 0, stream>>>(buf2, wprojT, b_proj, xout, n2_g, n2_b, buf2);
  // hidden = gelu(h2 @ w_fc1 + b) -> buf1 (bf16, N x 1024)
  k_gemm<256, 1024, 2><<<dim3(8, 1024), 256, 0, stream>>>(buf2, wfc1T, b_fc1, buf1, nullptr);
  // x += hidden @ w_fc2 + b   (final output in d_out)
  k_gemm<1024, 256, 1><<<dim3(2, 1024), 256, 0, stream>>>(buf1, wfc2T, b_fc2, nullptr, xout);
}